// Round 2
// baseline (358.186 us; speedup 1.0000x reference)
//
#include <hip/hip_runtime.h>
#include <hip/hip_bf16.h>

#define NN 50000
#define EE 800000

typedef short short8 __attribute__((ext_vector_type(8)));
typedef float f32x4 __attribute__((ext_vector_type(4)));
typedef float f32x2 __attribute__((ext_vector_type(2)));

union Frag16B { short8 s; int4 i; };
union H4 { _Float16 h[4]; uint2 u; };

static __device__ __forceinline__ unsigned short f2bf(float f) {
    union { float f; unsigned u; } v; v.f = f;
    unsigned r = v.u + 0x7FFF + ((v.u >> 16) & 1);   // RNE
    return (unsigned short)(r >> 16);
}
static __device__ __forceinline__ float bf_lo(unsigned int u) {
    return __uint_as_float(u << 16);
}
static __device__ __forceinline__ float bf_hi(unsigned int u) {
    return __uint_as_float(u & 0xFFFF0000u);
}
static __device__ __forceinline__ unsigned int pack2(float a, float b) {
    return (unsigned int)f2bf(a) | ((unsigned int)f2bf(b) << 16);
}

// ---------------- prep: fragment-major bf16 weight packing + pos->float4 ----
__global__ __launch_bounds__(256) void k_prep(
    const float* __restrict__ w1,  const float* __restrict__ att,
    const float* __restrict__ w2,
    const float* __restrict__ wft, const float* __restrict__ wcv,
    const float* __restrict__ pos,
    unsigned short* __restrict__ w1p, unsigned short* __restrict__ w2p,
    unsigned short* __restrict__ wftp, unsigned short* __restrict__ wcvp,
    float4* __restrict__ pos4)
{
    int gth = blockIdx.x * 256 + threadIdx.x;
    int lane = gth & 63, l15 = lane & 15, gg = lane >> 4;
    if (gth < 16384) {                       // w1p: kk<16, t<16, fold att[col]
        int t = (gth >> 6) & 15, kk = gth >> 10;
        int row = t * 16 + l15, c0 = kk * 32 + gg * 8;
        unsigned int pk[4];
        #pragma unroll
        for (int j = 0; j < 4; ++j) {
            int c = c0 + 2 * j;
            pk[j] = pack2(w1[row * 512 + c] * att[c],
                          w1[row * 512 + c + 1] * att[c + 1]);
        }
        *reinterpret_cast<uint4*>(w1p + (size_t)gth * 8) = make_uint4(pk[0], pk[1], pk[2], pk[3]);
    }
    if (gth < 4096) {                        // w2p: kk<8, t<8
        int t = (gth >> 6) & 7, kk = gth >> 9;
        int row = t * 16 + l15, c0 = kk * 32 + gg * 8;
        unsigned int pk[4];
        #pragma unroll
        for (int j = 0; j < 4; ++j) {
            int c = c0 + 2 * j;
            pk[j] = pack2(w2[row * 256 + c], w2[row * 256 + c + 1]);
        }
        *reinterpret_cast<uint4*>(w2p + (size_t)gth * 8) = make_uint4(pk[0], pk[1], pk[2], pk[3]);
    }
    if (gth < 2048) {                        // wftp / wcvp: kk<4, t<8
        int t = (gth >> 6) & 7, kk = gth >> 9;
        int row = t * 16 + l15, c0 = kk * 32 + gg * 8;
        unsigned int pa[4], pb[4];
        #pragma unroll
        for (int j = 0; j < 4; ++j) {
            int c = c0 + 2 * j;
            pa[j] = pack2(wft[row * 128 + c], wft[row * 128 + c + 1]);
            pb[j] = pack2(wcv[row * 128 + c], wcv[row * 128 + c + 1]);
        }
        *reinterpret_cast<uint4*>(wftp + (size_t)gth * 8) = make_uint4(pa[0], pa[1], pa[2], pa[3]);
        *reinterpret_cast<uint4*>(wcvp + (size_t)gth * 8) = make_uint4(pb[0], pb[1], pb[2], pb[3]);
    }
    if (gth < NN) {                          // pos -> padded float4
        pos4[gth] = make_float4(pos[gth * 3 + 0], pos[gth * 3 + 1], pos[gth * 3 + 2], 0.f);
    }
}

// ---------------- fused node GEMMs (MFMA): msg = (relu(x WftT+bft)) WcvT + bcv
__global__ __launch_bounds__(256) void k_ft_conv(
    const float* __restrict__ x,
    const unsigned short* __restrict__ wftp, const float* __restrict__ bft,
    const unsigned short* __restrict__ wcvp, const float* __restrict__ bcv,
    unsigned int* __restrict__ msg)          // bf16 [NN][128] as uint[NN][64]
{
    __shared__ unsigned int s_x[64 * 68];    // bf16 tile (reused for out)
    __shared__ unsigned short s_h[64 * 136];
    const int tid = threadIdx.x;
    const int w = tid >> 6, lane = tid & 63, l15 = lane & 15, g = lane >> 4;
    const int n0 = blockIdx.x * 64;

    #pragma unroll
    for (int i = 0; i < 8; ++i) {
        int lin = tid + i * 256;
        int row = lin >> 5, c4 = lin & 31;
        int ar = (n0 + row < NN) ? n0 + row : NN - 1;
        float4 v = *reinterpret_cast<const float4*>(x + (size_t)ar * 128 + c4 * 4);
        s_x[row * 68 + c4 * 2]     = pack2(v.x, v.y);
        s_x[row * 68 + c4 * 2 + 1] = pack2(v.z, v.w);
    }
    __syncthreads();

    float bftv[8], bcvv[8];
    #pragma unroll
    for (int t = 0; t < 8; ++t) { bftv[t] = bft[t * 16 + l15]; bcvv[t] = bcv[t * 16 + l15]; }

    const int4* Bf = reinterpret_cast<const int4*>(wftp);
    f32x4 acc[8];
    #pragma unroll
    for (int t = 0; t < 8; ++t) acc[t] = (f32x4){0.f, 0.f, 0.f, 0.f};
    #pragma unroll
    for (int kk = 0; kk < 4; ++kk) {
        Frag16B a;
        a.i = *reinterpret_cast<const int4*>(&s_x[(w * 16 + l15) * 68 + kk * 16 + g * 4]);
        #pragma unroll
        for (int t = 0; t < 8; ++t) {
            Frag16B b; b.i = Bf[(kk * 8 + t) * 64 + lane];
            acc[t] = __builtin_amdgcn_mfma_f32_16x16x32_bf16(a.s, b.s, acc[t], 0, 0, 0);
        }
    }
    #pragma unroll
    for (int t = 0; t < 8; ++t)
        #pragma unroll
        for (int r = 0; r < 4; ++r)
            s_h[(w * 16 + g * 4 + r) * 136 + t * 16 + l15] =
                f2bf(fmaxf(acc[t][r] + bftv[t], 0.f));
    __syncthreads();

    const int4* Bc = reinterpret_cast<const int4*>(wcvp);
    #pragma unroll
    for (int t = 0; t < 8; ++t) acc[t] = (f32x4){0.f, 0.f, 0.f, 0.f};
    #pragma unroll
    for (int kk = 0; kk < 4; ++kk) {
        Frag16B a;
        a.i = *reinterpret_cast<const int4*>(&s_h[(w * 16 + l15) * 136 + kk * 32 + g * 8]);
        #pragma unroll
        for (int t = 0; t < 8; ++t) {
            Frag16B b; b.i = Bc[(kk * 8 + t) * 64 + lane];
            acc[t] = __builtin_amdgcn_mfma_f32_16x16x32_bf16(a.s, b.s, acc[t], 0, 0, 0);
        }
    }
    unsigned short* s_o = reinterpret_cast<unsigned short*>(s_x);
    #pragma unroll
    for (int t = 0; t < 8; ++t)
        #pragma unroll
        for (int r = 0; r < 4; ++r)
            s_o[(w * 16 + g * 4 + r) * 136 + t * 16 + l15] = f2bf(acc[t][r] + bcvv[t]);
    __syncthreads();
    #pragma unroll
    for (int i = 0; i < 8; ++i) {
        int lin = tid + i * 256;
        int row = lin >> 5, cu2 = lin & 31;
        if (n0 + row < NN) {
            uint2 v;
            v.x = s_x[row * 68 + cu2 * 2];
            v.y = s_x[row * 68 + cu2 * 2 + 1];
            *reinterpret_cast<uint2*>(msg + (size_t)(n0 + row) * 64 + cu2 * 2) = v;
        }
    }
}

// ---------------- edge pass 1: {dist,dsum,s,d} record + degree + block max --
__global__ __launch_bounds__(256) void k_edge_pass1(
    const int* __restrict__ ei, const float4* __restrict__ pos4,
    float* __restrict__ blockmax, int* __restrict__ counts,
    float4* __restrict__ dde)
{
    __shared__ float smax[4];
    int e = blockIdx.x * 256 + threadIdx.x;       // grid covers EE exactly
    int s = ei[e], d = ei[EE + e];
    float4 ps = pos4[s], pd = pos4[d];
    float dx = ps.x - pd.x, dy = ps.y - pd.y, dz = ps.z - pd.z;
    float dist = sqrtf(dx * dx + dy * dy + dz * dz);
    float rinv = 1.f / (dist + 1e-8f);
    dde[e] = make_float4(dist, (dx + dy + dz) * rinv,
                         __int_as_float(s), __int_as_float(d));
    atomicAdd(&counts[d], 1);

    float m = dist;
    #pragma unroll
    for (int o = 32; o >= 1; o >>= 1)
        m = fmaxf(m, __shfl_xor(m, o));
    if ((threadIdx.x & 63) == 0) smax[threadIdx.x >> 6] = m;
    __syncthreads();
    if (threadIdx.x == 0)
        blockmax[blockIdx.x] = fmaxf(fmaxf(smax[0], smax[1]), fmaxf(smax[2], smax[3]));
}

// ---------------- 3-kernel exclusive scan over counts -----------------------
__global__ __launch_bounds__(256) void k_scan1(const int* __restrict__ counts,
    int* __restrict__ loc, int* __restrict__ bsum)
{
    __shared__ int sd[256];
    int i = blockIdx.x * 256 + threadIdx.x;
    int v = (i < NN) ? counts[i] : 0;
    sd[threadIdx.x] = v;
    __syncthreads();
    for (int ofs = 1; ofs < 256; ofs <<= 1) {
        int t = (threadIdx.x >= ofs) ? sd[threadIdx.x - ofs] : 0;
        __syncthreads();
        sd[threadIdx.x] += t;
        __syncthreads();
    }
    int incl = sd[threadIdx.x];
    if (i < NN) loc[i] = incl - v;
    if (threadIdx.x == 255) bsum[blockIdx.x] = incl;
}

// block 0: exclusive scan of bsum; block 1: dmax reduce over blockmax
__global__ __launch_bounds__(256) void k_scan2dmax(const int* __restrict__ bsum,
    int* __restrict__ bofs, int nb,
    const float* __restrict__ blockmax, float* __restrict__ dmax, int nmb)
{
    if (blockIdx.x == 0) {
        __shared__ int sd[256];
        int v = (threadIdx.x < nb) ? bsum[threadIdx.x] : 0;
        sd[threadIdx.x] = v;
        __syncthreads();
        for (int ofs = 1; ofs < 256; ofs <<= 1) {
            int t = (threadIdx.x >= ofs) ? sd[threadIdx.x - ofs] : 0;
            __syncthreads();
            sd[threadIdx.x] += t;
            __syncthreads();
        }
        bofs[threadIdx.x] = sd[threadIdx.x] - v;
    } else {
        __shared__ float smax[4];
        float m = 0.f;
        for (int i = threadIdx.x; i < nmb; i += 256) m = fmaxf(m, blockmax[i]);
        #pragma unroll
        for (int o = 32; o >= 1; o >>= 1)
            m = fmaxf(m, __shfl_xor(m, o));
        if ((threadIdx.x & 63) == 0) smax[threadIdx.x >> 6] = m;
        __syncthreads();
        if (threadIdx.x == 0)
            dmax[0] = fmaxf(fmaxf(smax[0], smax[1]), fmaxf(smax[2], smax[3]));
    }
}

__global__ __launch_bounds__(256) void k_scan3(const int* __restrict__ loc,
    const int* __restrict__ bofs, int* __restrict__ offs)
{
    int i = blockIdx.x * 256 + threadIdx.x;
    if (i < NN) offs[i] = loc[i] + bofs[blockIdx.x];
    if (i == 0) offs[NN] = EE;
}

// ---------------- edge pass 2: ab factors + packed CSR record ---------------
__global__ __launch_bounds__(256) void k_fill(
    const float4* __restrict__ dde,
    const float* __restrict__ dmaxp,
    const float* __restrict__ vfp, const float* __restrict__ vpar,
    const int* __restrict__ offs, int* __restrict__ cursor,
    uint4* __restrict__ csre)
{
    int e = blockIdx.x * 256 + threadIdx.x;       // grid covers EE exactly
    float4 v4 = dde[e];
    int s = __float_as_int(v4.z), d = __float_as_int(v4.w);
    float r = v4.x / dmaxp[0];
    float dsum = v4.y;
    float vf = vfp[0];
    H4 p;
    #pragma unroll
    for (int k = 0; k < 4; ++k) {
        float v = vf * fminf(r, vpar[k]);
        p.h[k] = (_Float16)(sqrtf(1.f - v * v + 1e-8f) / (1.f + v * dsum));
    }
    int slot = offs[d] + atomicAdd(&cursor[d], 1);
    csre[slot] = make_uint4((unsigned)s, p.u.x, p.u.y, 0u);
}

// ---------------- aggregation + fused BN partial stats ----------------------
// Half-wave per edge: 32 lanes x uint2 cover a 256B msg row; 2 edges in
// flight per issue slot. Main loop: 8-pair (16-edge) unpredicated batches
// (16 gathers outstanding). Remainder: predicated 4-pair (8-edge) batches —
// no serial 1-edge tail (waste <=7 zero-coeff edges, all same-line hits).
// f32x2 accumulators -> v_pk_fma_f32. Cross-half shfl_xor(32) reduce per
// node; BN partials in registers (fp32, pre-bf16), half 0 writes LDS.
__global__ __launch_bounds__(256) void k_agg(
    const int* __restrict__ offs, const uint4* __restrict__ csre,
    const unsigned int* __restrict__ msg,
    unsigned int* __restrict__ aggb,         // bf16 [NN][512] as uint[NN][256]
    float* __restrict__ bn_psum, float* __restrict__ bn_psq)
{
    __shared__ float s_bn[4 * 1024];         // [wave][32 vals][32 hl]
    const int tid = threadIdx.x;
    const int lane = tid & 63, w = tid >> 6;
    const int half = lane >> 5, hl = lane & 31;

    f32x2 ps2[8], pq2[8];                    // [k*2+c2]
    #pragma unroll
    for (int v = 0; v < 8; ++v) { ps2[v] = (f32x2){0.f, 0.f}; pq2[v] = (f32x2){0.f, 0.f}; }

    #pragma unroll 1
    for (int j = 0; j < 4; ++j) {
        int n = blockIdx.x * 16 + w * 4 + j;     // always < NN (3125*16 = 50000)
        int st = offs[n], en = offs[n + 1];
        f32x2 acc2[8];
        #pragma unroll
        for (int v = 0; v < 8; ++v) acc2[v] = (f32x2){0.f, 0.f};

        int e = st;
        // -------- main: 8 pairs = 16 edges, unpredicated ----------
        for (; e + 16 <= en; e += 16) {
            uint4 rr[8]; uint2 mm[8];
            #pragma unroll
            for (int p = 0; p < 8; ++p) rr[p] = csre[e + 2 * p + half];
            #pragma unroll
            for (int p = 0; p < 8; ++p)
                mm[p] = *reinterpret_cast<const uint2*>(msg + (size_t)rr[p].x * 64 + 2 * hl);
            #pragma unroll
            for (int p = 0; p < 8; ++p) {
                H4 hh; hh.u = make_uint2(rr[p].y, rr[p].z);
                f32x2 m01 = {bf_lo(mm[p].x), bf_hi(mm[p].x)};
                f32x2 m23 = {bf_lo(mm[p].y), bf_hi(mm[p].y)};
                #pragma unroll
                for (int k = 0; k < 4; ++k) {
                    float hk = (float)hh.h[k];
                    f32x2 h2 = {hk, hk};
                    acc2[k * 2]     += h2 * m01;
                    acc2[k * 2 + 1] += h2 * m23;
                }
            }
        }
        // -------- remainder: predicated 4-pair (8-edge) batches ----------
        for (; e < en; e += 8) {
            uint4 rr[4]; uint2 mm[4]; bool av[4];
            #pragma unroll
            for (int p = 0; p < 4; ++p) {
                int ee = e + 2 * p + half;
                av[p] = ee < en;
                rr[p] = csre[av[p] ? ee : en - 1];
            }
            #pragma unroll
            for (int p = 0; p < 4; ++p)
                mm[p] = *reinterpret_cast<const uint2*>(msg + (size_t)rr[p].x * 64 + 2 * hl);
            #pragma unroll
            for (int p = 0; p < 4; ++p) {
                H4 hh; hh.u = make_uint2(rr[p].y, rr[p].z);
                f32x2 m01 = {bf_lo(mm[p].x), bf_hi(mm[p].x)};
                f32x2 m23 = {bf_lo(mm[p].y), bf_hi(mm[p].y)};
                #pragma unroll
                for (int k = 0; k < 4; ++k) {
                    float hk = av[p] ? (float)hh.h[k] : 0.f;
                    f32x2 h2 = {hk, hk};
                    acc2[k * 2]     += h2 * m01;
                    acc2[k * 2 + 1] += h2 * m23;
                }
            }
        }

        // -------- cross-half reduce: both halves end with full node sums ----
        #pragma unroll
        for (int v = 0; v < 8; ++v) {
            acc2[v].x += __shfl_xor(acc2[v].x, 32);
            acc2[v].y += __shfl_xor(acc2[v].y, 32);
        }

        // -------- write: half h owns k = 2h, 2h+1; col = k*128 + 4*hl + c ---
        unsigned int* o = aggb + (size_t)n * 256;
        #pragma unroll
        for (int kk = 0; kk < 2; ++kk) {
            int k = 2 * half + kk;
            uint2 vv;
            vv.x = pack2(acc2[k * 2].x, acc2[k * 2].y);
            vv.y = pack2(acc2[k * 2 + 1].x, acc2[k * 2 + 1].y);
            *reinterpret_cast<uint2*>(o + k * 64 + 2 * hl) = vv;
        }

        // -------- BN partials (both halves hold identical full sums) --------
        #pragma unroll
        for (int v = 0; v < 8; ++v) {
            ps2[v] += acc2[v];
            pq2[v] += acc2[v] * acc2[v];
        }
    }

    // per-wave partials -> LDS; only half 0 writes (halves are duplicates)
    float* sw = s_bn + w * 1024;
    if (half == 0) {
        #pragma unroll
        for (int v = 0; v < 8; ++v) {            // v = k*2 + c2; val idx k*4+2*c2+{0,1}
            sw[(2 * v) * 32 + hl]       = ps2[v].x;
            sw[(2 * v + 1) * 32 + hl]   = ps2[v].y;
            sw[512 + (2 * v) * 32 + hl]     = pq2[v].x;
            sw[512 + (2 * v + 1) * 32 + hl] = pq2[v].y;
        }
    }
    __syncthreads();

    // cross-wave reduce + one atomic per entry (1024 entries / 256 threads)
    int part = (blockIdx.x & 31) * 512;
    #pragma unroll
    for (int kq = 0; kq < 4; ++kq) {
        int idx = tid + kq * 256;                // 0..1023
        float s = s_bn[idx] + s_bn[1024 + idx] + s_bn[2048 + idx] + s_bn[3072 + idx];
        int vv = (idx >> 5) & 15, hh = idx & 31;
        int k = vv >> 2, c = vv & 3;
        int col = k * 128 + 4 * hh + c;
        if (idx < 512) atomicAdd(&bn_psum[part + col], s);
        else           atomicAdd(&bn_psq[part + col], s);
    }
}

__global__ __launch_bounds__(256) void k_bnfin(const float* __restrict__ bn_psum,
    const float* __restrict__ bn_psq, const float* __restrict__ bng,
    const float* __restrict__ bnbeta, float* __restrict__ bns, float* __restrict__ bnbv)
{
    int c = blockIdx.x * 256 + threadIdx.x;
    if (c >= 512) return;
    float s = 0.f, q = 0.f;
    #pragma unroll 8
    for (int p = 0; p < 32; ++p) {
        s += bn_psum[p * 512 + c];
        q += bn_psq[p * 512 + c];
    }
    float mean = s * (1.f / NN);
    float var = q * (1.f / NN) - mean * mean;
    float sc = bng[c] / sqrtf(var + 1e-5f);
    bns[c] = sc;
    bnbv[c] = bnbeta[c] - mean * sc;
}

// ---------------- final fused MFMA: col-split waves, 32-node tile -----------
// Block = 4 waves = 2 node-groups (ng) x 2 col-halves (ch). Wave: 16 nodes x
// 128 GEMM1 cols (acc1[8]=32 AGPR) and 16 nodes x 64 GEMM2 cols (acc2[4]=16).
// Total ~118 regs -> 4 waves/EU. Full z stage; LN = 2-wave LDS partials.
__global__ __launch_bounds__(256) void k_final(
    const unsigned int* __restrict__ aggb,
    const float* __restrict__ bns, const float* __restrict__ bnb,
    const unsigned short* __restrict__ w1p, const float* __restrict__ b1,
    const float* __restrict__ lng, const float* __restrict__ lnb,
    const unsigned short* __restrict__ w2p, const float* __restrict__ b2,
    float* __restrict__ out)
{
    __shared__ unsigned int s_z[32 * 260];   // 33280 B; t matrix aliases below
    __shared__ float s_lng[256], s_lnb[256];
    __shared__ float s_ps[2][32], s_pq[2][32];
    __shared__ float s_mu[32], s_iv[32];
    unsigned short* s_ts = reinterpret_cast<unsigned short*>(s_z);  // [32][264]

    const int tid = threadIdx.x;
    const int w = tid >> 6, lane = tid & 63, l15 = lane & 15, g = lane >> 4;
    const int ng = w & 1, ch = w >> 1;
    const int n0 = blockIdx.x * 32;

    s_lng[tid] = lng[tid];
    s_lnb[tid] = lnb[tid];

    // stage z = bf16(relu(agg*scale+shift)); thread owns uint col = tid
    float2 sv = *reinterpret_cast<const float2*>(bns + 2 * tid);
    float2 bv = *reinterpret_cast<const float2*>(bnb + 2 * tid);
    #pragma unroll 8
    for (int i = 0; i < 32; ++i) {
        int ar = (n0 + i < NN) ? n0 + i : NN - 1;
        unsigned int u = aggb[(size_t)ar * 256 + tid];
        float z0 = fmaxf(fmaf(bf_lo(u), sv.x, bv.x), 0.f);
        float z1 = fmaxf(fmaf(bf_hi(u), sv.y, bv.y), 0.f);
        s_z[i * 260 + tid] = pack2(z0, z1);
    }
    __syncthreads();

    // ---------------- GEMM1: rows ng*16+l15, out tiles ch*8+j (j<8) ---------
    const unsigned int* zrow = s_z + (ng * 16 + l15) * 260;
    const int4* B1 = reinterpret_cast<const int4*>(w1p);
    f32x4 acc1[8];
    #pragma unroll
    for (int j = 0; j < 8; ++j) acc1[j] = (f32x4){0.f, 0.f, 0.f, 0.f};

    #pragma unroll 2
    for (int kk = 0; kk < 16; ++kk) {
        Frag16B a;
        a.i = *reinterpret_cast<const int4*>(zrow + kk * 16 + g * 4);
        #pragma unroll
        for (int j = 0; j < 8; ++j) {
            Frag16B b; b.i = B1[(kk * 16 + ch * 8 + j) * 64 + lane];
            acc1[j] = __builtin_amdgcn_mfma_f32_16x16x32_bf16(a.s, b.s, acc1[j], 0, 0, 0);
        }
    }
    __syncthreads();   // all z reads done before t overwrites the buffer

    // ---------------- bias + t stash + LN partials (per col-half) -----------
    float b1v[8];
    #pragma unroll
    for (int j = 0; j < 8; ++j) b1v[j] = b1[(ch * 8 + j) * 16 + l15];

    float ssum[4] = {0, 0, 0, 0}, sq[4] = {0, 0, 0, 0};
    #pragma unroll
    for (int j = 0; j < 8; ++j) {
        float bvv = b1v[j];
        #pragma unroll
        for (int r = 0; r < 4; ++r) {
            float tv = acc1[j][r] + bvv;
            ssum[r] += tv;
            sq[r] = fmaf(tv, tv, sq[r]);
            s_ts[(ng * 16 + g * 4 + r) * 264 + (ch * 8 + j) * 16 + l15] = f2bf(tv);
        }
    }
    #pragma unroll
    for (int m = 1; m < 16; m <<= 1) {
        #pragma unroll
        for (int r = 0; r < 4; ++r) {
            ssum[r] += __shfl_xor(ssum[r], m);
            sq[r]   += __shfl_xor(sq[r], m);
        }
    }
    if (l15 < 4) {
        float svv = l15 == 0 ? ssum[0] : l15 == 1 ? ssum[1] : l15 == 2 ? ssum[2] : ssum[3];
        float qv  = l15 == 0 ? sq[0]   : l15 == 1 ? sq[1]   : l15 == 2 ? sq[2]   : sq[3];
        s_ps[ch][ng * 16 + g * 4 + l15] = svv;
        s_pq[ch][ng * 16 + g * 4 + l15] = qv;
    }
    __syncthreads();

    if (tid < 32) {
        float s = s_ps[0][tid] + s_ps[1][tid];
        float q = s_pq[0][tid] + s_pq[1][tid];
        float mean = s * (1.f / 256.f);
        float var = q * (1.f / 256.f) - mean * mean;
        s_mu[tid] = mean;
        s_iv[tid] = 1.f / sqrtf(var + 1e-5f);
    }
    __syncthreads();

    // ---------------- GEMM2: K=256 over t; out tiles ch*4+j (j<4) -----------
    const float mu_m = s_mu[ng * 16 + l15];
    const float iv_m = s_iv[ng * 16 + l15];
    const int4* B2 = reinterpret_cast<const int4*>(w2p);
    const unsigned short* trow = s_ts + (ng * 16 + l15) * 264;

    f32x4 acc2[4];
    #pragma unroll
    for (int j = 0; j < 4; ++j) acc2[j] = (f32x4){0.f, 0.f, 0.f, 0.f};

    #pragma unroll 2
    for (int kk = 0; kk < 8; ++kk) {
        const int kb = kk * 32 + g * 8;
        int4 traw = *reinterpret_cast<const int4*>(trow + kb);
        const unsigned short* tu = reinterpret_cast<const unsigned short*>(&traw);
        short8 af;
        #pragma unroll
        for (int j = 0; j < 8; ++j) {
            float tv = __uint_as_float(((unsigned int)tu[j]) << 16);
            float rn = fmaxf(fmaf((tv - mu_m) * iv_m, s_lng[kb + j], s_lnb[kb + j]), 0.f);
            af[j] = (short)f2bf(rn);
        }
        #pragma unroll
        for (int j = 0; j < 4; ++j) {
            Frag16B b; b.i = B2[(kk * 8 + ch * 4 + j) * 64 + lane];
            acc2[j] = __builtin_amdgcn_mfma_f32_16x16x32_bf16(af, b.s, acc2[j], 0, 0, 0);
        }
    }

    float b2v[4];
    #pragma unroll
    for (int j = 0; j < 4; ++j) b2v[j] = b2[(ch * 4 + j) * 16 + l15];

    #pragma unroll
    for (int j = 0; j < 4; ++j) {
        #pragma unroll
        for (int r = 0; r < 4; ++r) {
            int n = n0 + ng * 16 + g * 4 + r;
            if (n < NN)
                out[(size_t)n * 128 + (ch * 4 + j) * 16 + l15] = acc2[j][r] + b2v[j];
        }
    }
}

// ---------------------------------------------------------------------------
extern "C" void kernel_launch(void* const* d_in, const int* in_sizes, int n_in,
                              void* d_out, int out_size, void* d_ws, size_t ws_size,
                              hipStream_t stream)
{
    const float* x    = (const float*)d_in[0];
    const int*   ei   = (const int*)d_in[1];
    const float* pos  = (const float*)d_in[2];
    const float* wft  = (const float*)d_in[3];
    const float* bft  = (const float*)d_in[4];
    const float* wcv  = (const float*)d_in[5];
    const float* bcv  = (const float*)d_in[6];
    const float* vfp  = (const float*)d_in[7];
    const float* vpar = (const float*)d_in[8];
    const float* bng  = (const float*)d_in[9];
    const float* bnbe = (const float*)d_in[10];
    const float* att  = (const float*)d_in[11];
    const float* w1   = (const float*)d_in[12];
    const float* b1   = (const float*)d_in[13];
    const float* lng  = (const float*)d_in[14];
    const float* lnb  = (const float*)d_in[15];
    const float* w2   = (const float*)d_in[16];
    const float* b2   = (const float*)d_in[17];
    float* out = (float*)d_out;

    float* ws = (float*)d_ws;
    size_t off = 0;
    unsigned int* msg  = (unsigned int*)(ws + off); off += (size_t)NN * 64;    // bf16 [N][128]
    unsigned int* aggb = (unsigned int*)(ws + off); off += (size_t)NN * 256;   // bf16 [N][512]
    unsigned short* w1p  = (unsigned short*)(ws + off); off += 65536;
    unsigned short* w2p  = (unsigned short*)(ws + off); off += 16384;
    unsigned short* wftp = (unsigned short*)(ws + off); off += 8192;
    unsigned short* wcvp = (unsigned short*)(ws + off); off += 8192;
    float4* pos4 = (float4*)(ws + off); off += (size_t)NN * 4;
    float* bns  = ws + off; off += 512;
    float* bnbv = ws + off; off += 512;
    float4* dde = (float4*)(ws + off); off += (size_t)EE * 4;   // {dist,dsum,s,d}
    uint4* csre = (uint4*)(ws + off); off += (size_t)EE * 4;    // {src, ab01, ab23, pad}
    int* offs   = (int*)(ws + off); off += NN + 4;
    int* loc    = (int*)(ws + off); off += NN;
    int* bsum   = (int*)(ws + off); off += 256;
    int* bofs   = (int*)(ws + off); off += 256;
    float* blockmax = ws + off; off += 3136;
    float* dmax = ws + off; off += 4;
    size_t zstart = off;
    float* bn_psum = ws + off; off += 32 * 512;
    float* bn_psq  = ws + off; off += 32 * 512;
    int* counts = (int*)(ws + off); off += NN;
    int* cursor = (int*)(ws + off); off += NN;
    size_t zend = off;

    hipMemsetAsync(ws + zstart, 0, (zend - zstart) * sizeof(float), stream);

    k_prep<<<196, 256, 0, stream>>>(w1, att, w2, wft, wcv, pos, w1p, w2p, wftp, wcvp, pos4);
    k_ft_conv<<<782, 256, 0, stream>>>(x, wftp, bft, wcvp, bcv, msg);
    k_edge_pass1<<<3125, 256, 0, stream>>>(ei, pos4, blockmax, counts, dde);
    k_scan1<<<196, 256, 0, stream>>>(counts, loc, bsum);
    k_scan2dmax<<<2, 256, 0, stream>>>(bsum, bofs, 196, blockmax, dmax, 3125);
    k_scan3<<<196, 256, 0, stream>>>(loc, bofs, offs);
    k_fill<<<3125, 256, 0, stream>>>(dde, dmax, vfp, vpar, offs, cursor, csre);
    k_agg<<<3125, 256, 0, stream>>>(offs, csre, msg, aggb, bn_psum, bn_psq);
    k_bnfin<<<2, 256, 0, stream>>>(bn_psum, bn_psq, bng, bnbe, bns, bnbv);
    k_final<<<1563, 256, 0, stream>>>(aggb, bns, bnbv, w1p, b1, lng, lnb, w2p, b2, out);
}

// Round 4
// 328.563 us; speedup vs baseline: 1.0902x; 1.0902x over previous
//
#include <hip/hip_runtime.h>
#include <hip/hip_bf16.h>

#define NN 50000
#define EE 800000

typedef short short8 __attribute__((ext_vector_type(8)));
typedef float f32x4 __attribute__((ext_vector_type(4)));

union Frag16B { short8 s; int4 i; };
union H4 { _Float16 h[4]; uint2 u; };

static __device__ __forceinline__ unsigned short f2bf(float f) {
    union { float f; unsigned u; } v; v.f = f;
    unsigned r = v.u + 0x7FFF + ((v.u >> 16) & 1);   // RNE
    return (unsigned short)(r >> 16);
}
static __device__ __forceinline__ float bf_lo(unsigned int u) {
    return __uint_as_float(u << 16);
}
static __device__ __forceinline__ float bf_hi(unsigned int u) {
    return __uint_as_float(u & 0xFFFF0000u);
}
static __device__ __forceinline__ unsigned int pack2(float a, float b) {
    return (unsigned int)f2bf(a) | ((unsigned int)f2bf(b) << 16);
}

// ---------------- prep: fragment-major bf16 weight packing + pos->float4 ----
__global__ __launch_bounds__(256) void k_prep(
    const float* __restrict__ w1,  const float* __restrict__ att,
    const float* __restrict__ w2,
    const float* __restrict__ wft, const float* __restrict__ wcv,
    const float* __restrict__ pos,
    unsigned short* __restrict__ w1p, unsigned short* __restrict__ w2p,
    unsigned short* __restrict__ wftp, unsigned short* __restrict__ wcvp,
    float4* __restrict__ pos4)
{
    int gth = blockIdx.x * 256 + threadIdx.x;
    int lane = gth & 63, l15 = lane & 15, gg = lane >> 4;
    if (gth < 16384) {                       // w1p: kk<16, t<16, fold att[col]
        int t = (gth >> 6) & 15, kk = gth >> 10;
        int row = t * 16 + l15, c0 = kk * 32 + gg * 8;
        unsigned int pk[4];
        #pragma unroll
        for (int j = 0; j < 4; ++j) {
            int c = c0 + 2 * j;
            pk[j] = pack2(w1[row * 512 + c] * att[c],
                          w1[row * 512 + c + 1] * att[c + 1]);
        }
        *reinterpret_cast<uint4*>(w1p + (size_t)gth * 8) = make_uint4(pk[0], pk[1], pk[2], pk[3]);
    }
    if (gth < 4096) {                        // w2p: kk<8, t<8
        int t = (gth >> 6) & 7, kk = gth >> 9;
        int row = t * 16 + l15, c0 = kk * 32 + gg * 8;
        unsigned int pk[4];
        #pragma unroll
        for (int j = 0; j < 4; ++j) {
            int c = c0 + 2 * j;
            pk[j] = pack2(w2[row * 256 + c], w2[row * 256 + c + 1]);
        }
        *reinterpret_cast<uint4*>(w2p + (size_t)gth * 8) = make_uint4(pk[0], pk[1], pk[2], pk[3]);
    }
    if (gth < 2048) {                        // wftp / wcvp: kk<4, t<8
        int t = (gth >> 6) & 7, kk = gth >> 9;
        int row = t * 16 + l15, c0 = kk * 32 + gg * 8;
        unsigned int pa[4], pb[4];
        #pragma unroll
        for (int j = 0; j < 4; ++j) {
            int c = c0 + 2 * j;
            pa[j] = pack2(wft[row * 128 + c], wft[row * 128 + c + 1]);
            pb[j] = pack2(wcv[row * 128 + c], wcv[row * 128 + c + 1]);
        }
        *reinterpret_cast<uint4*>(wftp + (size_t)gth * 8) = make_uint4(pa[0], pa[1], pa[2], pa[3]);
        *reinterpret_cast<uint4*>(wcvp + (size_t)gth * 8) = make_uint4(pb[0], pb[1], pb[2], pb[3]);
    }
    if (gth < NN) {                          // pos -> padded float4
        pos4[gth] = make_float4(pos[gth * 3 + 0], pos[gth * 3 + 1], pos[gth * 3 + 2], 0.f);
    }
}

// ---------------- fused node GEMMs (MFMA): msg = (relu(x WftT+bft)) WcvT + bcv
__global__ __launch_bounds__(256) void k_ft_conv(
    const float* __restrict__ x,
    const unsigned short* __restrict__ wftp, const float* __restrict__ bft,
    const unsigned short* __restrict__ wcvp, const float* __restrict__ bcv,
    unsigned int* __restrict__ msg)          // bf16 [NN][128] as uint[NN][64]
{
    __shared__ unsigned int s_x[64 * 68];    // bf16 tile (reused for out)
    __shared__ unsigned short s_h[64 * 136];
    const int tid = threadIdx.x;
    const int w = tid >> 6, lane = tid & 63, l15 = lane & 15, g = lane >> 4;
    const int n0 = blockIdx.x * 64;

    #pragma unroll
    for (int i = 0; i < 8; ++i) {
        int lin = tid + i * 256;
        int row = lin >> 5, c4 = lin & 31;
        int ar = (n0 + row < NN) ? n0 + row : NN - 1;
        float4 v = *reinterpret_cast<const float4*>(x + (size_t)ar * 128 + c4 * 4);
        s_x[row * 68 + c4 * 2]     = pack2(v.x, v.y);
        s_x[row * 68 + c4 * 2 + 1] = pack2(v.z, v.w);
    }
    __syncthreads();

    float bftv[8], bcvv[8];
    #pragma unroll
    for (int t = 0; t < 8; ++t) { bftv[t] = bft[t * 16 + l15]; bcvv[t] = bcv[t * 16 + l15]; }

    const int4* Bf = reinterpret_cast<const int4*>(wftp);
    f32x4 acc[8];
    #pragma unroll
    for (int t = 0; t < 8; ++t) acc[t] = (f32x4){0.f, 0.f, 0.f, 0.f};
    #pragma unroll
    for (int kk = 0; kk < 4; ++kk) {
        Frag16B a;
        a.i = *reinterpret_cast<const int4*>(&s_x[(w * 16 + l15) * 68 + kk * 16 + g * 4]);
        #pragma unroll
        for (int t = 0; t < 8; ++t) {
            Frag16B b; b.i = Bf[(kk * 8 + t) * 64 + lane];
            acc[t] = __builtin_amdgcn_mfma_f32_16x16x32_bf16(a.s, b.s, acc[t], 0, 0, 0);
        }
    }
    #pragma unroll
    for (int t = 0; t < 8; ++t)
        #pragma unroll
        for (int r = 0; r < 4; ++r)
            s_h[(w * 16 + g * 4 + r) * 136 + t * 16 + l15] =
                f2bf(fmaxf(acc[t][r] + bftv[t], 0.f));
    __syncthreads();

    const int4* Bc = reinterpret_cast<const int4*>(wcvp);
    #pragma unroll
    for (int t = 0; t < 8; ++t) acc[t] = (f32x4){0.f, 0.f, 0.f, 0.f};
    #pragma unroll
    for (int kk = 0; kk < 4; ++kk) {
        Frag16B a;
        a.i = *reinterpret_cast<const int4*>(&s_h[(w * 16 + l15) * 136 + kk * 32 + g * 8]);
        #pragma unroll
        for (int t = 0; t < 8; ++t) {
            Frag16B b; b.i = Bc[(kk * 8 + t) * 64 + lane];
            acc[t] = __builtin_amdgcn_mfma_f32_16x16x32_bf16(a.s, b.s, acc[t], 0, 0, 0);
        }
    }
    unsigned short* s_o = reinterpret_cast<unsigned short*>(s_x);
    #pragma unroll
    for (int t = 0; t < 8; ++t)
        #pragma unroll
        for (int r = 0; r < 4; ++r)
            s_o[(w * 16 + g * 4 + r) * 136 + t * 16 + l15] = f2bf(acc[t][r] + bcvv[t]);
    __syncthreads();
    #pragma unroll
    for (int i = 0; i < 8; ++i) {
        int lin = tid + i * 256;
        int row = lin >> 5, cu2 = lin & 31;
        if (n0 + row < NN) {
            uint2 v;
            v.x = s_x[row * 68 + cu2 * 2];
            v.y = s_x[row * 68 + cu2 * 2 + 1];
            *reinterpret_cast<uint2*>(msg + (size_t)(n0 + row) * 64 + cu2 * 2) = v;
        }
    }
}

// ---------------- edge pass 1: {dist,dsum,s,d} record + degree + block max --
__global__ __launch_bounds__(256) void k_edge_pass1(
    const int* __restrict__ ei, const float4* __restrict__ pos4,
    float* __restrict__ blockmax, int* __restrict__ counts,
    float4* __restrict__ dde)
{
    __shared__ float smax[4];
    int e = blockIdx.x * 256 + threadIdx.x;       // grid covers EE exactly
    int s = ei[e], d = ei[EE + e];
    float4 ps = pos4[s], pd = pos4[d];
    float dx = ps.x - pd.x, dy = ps.y - pd.y, dz = ps.z - pd.z;
    float dist = sqrtf(dx * dx + dy * dy + dz * dz);
    float rinv = 1.f / (dist + 1e-8f);
    dde[e] = make_float4(dist, (dx + dy + dz) * rinv,
                         __int_as_float(s), __int_as_float(d));
    atomicAdd(&counts[d], 1);

    float m = dist;
    #pragma unroll
    for (int o = 32; o >= 1; o >>= 1)
        m = fmaxf(m, __shfl_xor(m, o));
    if ((threadIdx.x & 63) == 0) smax[threadIdx.x >> 6] = m;
    __syncthreads();
    if (threadIdx.x == 0)
        blockmax[blockIdx.x] = fmaxf(fmaxf(smax[0], smax[1]), fmaxf(smax[2], smax[3]));
}

// ---------------- 3-kernel exclusive scan over counts -----------------------
__global__ __launch_bounds__(256) void k_scan1(const int* __restrict__ counts,
    int* __restrict__ loc, int* __restrict__ bsum)
{
    __shared__ int sd[256];
    int i = blockIdx.x * 256 + threadIdx.x;
    int v = (i < NN) ? counts[i] : 0;
    sd[threadIdx.x] = v;
    __syncthreads();
    for (int ofs = 1; ofs < 256; ofs <<= 1) {
        int t = (threadIdx.x >= ofs) ? sd[threadIdx.x - ofs] : 0;
        __syncthreads();
        sd[threadIdx.x] += t;
        __syncthreads();
    }
    int incl = sd[threadIdx.x];
    if (i < NN) loc[i] = incl - v;
    if (threadIdx.x == 255) bsum[blockIdx.x] = incl;
}

// block 0: exclusive scan of bsum; block 1: dmax reduce over blockmax
__global__ __launch_bounds__(256) void k_scan2dmax(const int* __restrict__ bsum,
    int* __restrict__ bofs, int nb,
    const float* __restrict__ blockmax, float* __restrict__ dmax, int nmb)
{
    if (blockIdx.x == 0) {
        __shared__ int sd[256];
        int v = (threadIdx.x < nb) ? bsum[threadIdx.x] : 0;
        sd[threadIdx.x] = v;
        __syncthreads();
        for (int ofs = 1; ofs < 256; ofs <<= 1) {
            int t = (threadIdx.x >= ofs) ? sd[threadIdx.x - ofs] : 0;
            __syncthreads();
            sd[threadIdx.x] += t;
            __syncthreads();
        }
        bofs[threadIdx.x] = sd[threadIdx.x] - v;
    } else {
        __shared__ float smax[4];
        float m = 0.f;
        for (int i = threadIdx.x; i < nmb; i += 256) m = fmaxf(m, blockmax[i]);
        #pragma unroll
        for (int o = 32; o >= 1; o >>= 1)
            m = fmaxf(m, __shfl_xor(m, o));
        if ((threadIdx.x & 63) == 0) smax[threadIdx.x >> 6] = m;
        __syncthreads();
        if (threadIdx.x == 0)
            dmax[0] = fmaxf(fmaxf(smax[0], smax[1]), fmaxf(smax[2], smax[3]));
    }
}

__global__ __launch_bounds__(256) void k_scan3(const int* __restrict__ loc,
    const int* __restrict__ bofs, int* __restrict__ offs)
{
    int i = blockIdx.x * 256 + threadIdx.x;
    if (i < NN) offs[i] = loc[i] + bofs[blockIdx.x];
    if (i == 0) offs[NN] = EE;
}

// ---------------- edge pass 2: ab factors + SoA CSR record ------------------
__global__ __launch_bounds__(256) void k_fill(
    const float4* __restrict__ dde,
    const float* __restrict__ dmaxp,
    const float* __restrict__ vfp, const float* __restrict__ vpar,
    const int* __restrict__ offs, int* __restrict__ cursor,
    int* __restrict__ srcs, uint2* __restrict__ abe)
{
    int e = blockIdx.x * 256 + threadIdx.x;       // grid covers EE exactly
    float4 v4 = dde[e];
    int s = __float_as_int(v4.z), d = __float_as_int(v4.w);
    float r = v4.x / dmaxp[0];
    float dsum = v4.y;
    float vf = vfp[0];
    H4 p;
    #pragma unroll
    for (int k = 0; k < 4; ++k) {
        float v = vf * fminf(r, vpar[k]);
        p.h[k] = (_Float16)(sqrtf(1.f - v * v + 1e-8f) / (1.f + v * dsum));
    }
    int slot = offs[d] + atomicAdd(&cursor[d], 1);
    srcs[slot] = s;
    abe[slot] = p.u;
}

// ---------------- aggregation + fused BN partial stats ----------------------
// Full wave per edge (lane owns msg uint col = lane). Grid-stride: 2048
// blocks = 32 waves/CU resident, 8192 waves cover 50000 nodes (~6 each) —
// perfect packing, no block tail, BN partials amortized (2M atomics).
// SoA edge records: srcs[]/abe[] indexed wave-uniformly -> compiler keeps
// indices+coefficients in SGPRs (s_load); only real gathers hit VMEM.
// Tail predication is wave-uniform (scalar cselect, zero coeffs) — no
// serial 1-edge tail. ~45 VGPR target -> 8 waves/SIMD.
__global__ __launch_bounds__(256) void k_agg(
    const int* __restrict__ offs, const int* __restrict__ srcs,
    const uint2* __restrict__ abe, const unsigned int* __restrict__ msg,
    unsigned int* __restrict__ aggb,         // bf16 [NN][512] as uint[NN][256]
    float* __restrict__ bn_psum, float* __restrict__ bn_psq)
{
    __shared__ float s_bn[4 * 1024];         // [wave][16 vals][64 lanes]
    const int tid = threadIdx.x;
    const int lane = tid & 63;
    const int w = __builtin_amdgcn_readfirstlane(tid >> 6);
    const int gw = (blockIdx.x << 2) | w;    // 0..8191

    float ps0 = 0, ps1 = 0, ps2 = 0, ps3 = 0, ps4 = 0, ps5 = 0, ps6 = 0, ps7 = 0;
    float pq0 = 0, pq1 = 0, pq2 = 0, pq3 = 0, pq4 = 0, pq5 = 0, pq6 = 0, pq7 = 0;

    for (int n = gw; n < NN; n += 8192) {
        int st = __builtin_amdgcn_readfirstlane(offs[n]);
        int en = __builtin_amdgcn_readfirstlane(offs[n + 1]);
        float a00 = 0, a10 = 0, a20 = 0, a30 = 0, a01 = 0, a11 = 0, a21 = 0, a31 = 0;

        for (int e = st; e < en; e += 8) {
            int idx[8];
            unsigned int uu[8];
            #pragma unroll
            for (int j = 0; j < 8; ++j) {
                int ee = e + j;
                idx[j] = (ee < en) ? ee : en - 1;       // wave-uniform clamp
            }
            #pragma unroll
            for (int j = 0; j < 8; ++j)
                uu[j] = msg[(size_t)srcs[idx[j]] * 64 + lane];
            #pragma unroll
            for (int j = 0; j < 8; ++j) {
                uint2 a = abe[idx[j]];
                bool valid = (e + j) < en;              // wave-uniform
                a.x = valid ? a.x : 0u;
                a.y = valid ? a.y : 0u;
                H4 p; p.u = a;
                float m0 = bf_lo(uu[j]), m1 = bf_hi(uu[j]);
                a00 = fmaf((float)p.h[0], m0, a00); a01 = fmaf((float)p.h[0], m1, a01);
                a10 = fmaf((float)p.h[1], m0, a10); a11 = fmaf((float)p.h[1], m1, a11);
                a20 = fmaf((float)p.h[2], m0, a20); a21 = fmaf((float)p.h[2], m1, a21);
                a30 = fmaf((float)p.h[3], m0, a30); a31 = fmaf((float)p.h[3], m1, a31);
            }
        }

        unsigned int* o = aggb + (size_t)n * 256 + lane;   // col c = k*128 + h
        o[0]   = pack2(a00, a01);
        o[64]  = pack2(a10, a11);
        o[128] = pack2(a20, a21);
        o[192] = pack2(a30, a31);

        ps0 += a00; pq0 = fmaf(a00, a00, pq0);
        ps1 += a01; pq1 = fmaf(a01, a01, pq1);
        ps2 += a10; pq2 = fmaf(a10, a10, pq2);
        ps3 += a11; pq3 = fmaf(a11, a11, pq3);
        ps4 += a20; pq4 = fmaf(a20, a20, pq4);
        ps5 += a21; pq5 = fmaf(a21, a21, pq5);
        ps6 += a30; pq6 = fmaf(a30, a30, pq6);
        ps7 += a31; pq7 = fmaf(a31, a31, pq7);
    }

    // per-wave partials -> LDS
    float* sw = s_bn + w * 1024 + lane;
    sw[0 * 64] = ps0; sw[1 * 64] = ps1; sw[2 * 64] = ps2; sw[3 * 64] = ps3;
    sw[4 * 64] = ps4; sw[5 * 64] = ps5; sw[6 * 64] = ps6; sw[7 * 64] = ps7;
    sw[8 * 64] = pq0; sw[9 * 64] = pq1; sw[10 * 64] = pq2; sw[11 * 64] = pq3;
    sw[12 * 64] = pq4; sw[13 * 64] = pq5; sw[14 * 64] = pq6; sw[15 * 64] = pq7;
    __syncthreads();

    // cross-wave reduce + one atomic per entry (1024 entries / 256 threads)
    int part = (blockIdx.x & 31) * 512;
    #pragma unroll
    for (int k = 0; k < 4; ++k) {
        int idx = tid + k * 256;                 // 0..1023
        float s = s_bn[idx] + s_bn[1024 + idx] + s_bn[2048 + idx] + s_bn[3072 + idx];
        int v = idx >> 6, ln = idx & 63;
        int col = ((v & 7) >> 1) * 128 + 2 * ln + (v & 1);
        if (v < 8) atomicAdd(&bn_psum[part + col], s);
        else       atomicAdd(&bn_psq[part + col], s);
    }
}

__global__ __launch_bounds__(256) void k_bnfin(const float* __restrict__ bn_psum,
    const float* __restrict__ bn_psq, const float* __restrict__ bng,
    const float* __restrict__ bnbeta, float* __restrict__ bns, float* __restrict__ bnbv)
{
    int c = blockIdx.x * 256 + threadIdx.x;
    if (c >= 512) return;
    float s = 0.f, q = 0.f;
    #pragma unroll 8
    for (int p = 0; p < 32; ++p) {
        s += bn_psum[p * 512 + c];
        q += bn_psq[p * 512 + c];
    }
    float mean = s * (1.f / NN);
    float var = q * (1.f / NN) - mean * mean;
    float sc = bng[c] / sqrtf(var + 1e-5f);
    bns[c] = sc;
    bnbv[c] = bnbeta[c] - mean * sc;
}

// ---------------- final fused MFMA: col-split waves, 32-node tile -----------
// Block = 4 waves = 2 node-groups (ng) x 2 col-halves (ch). Wave: 16 nodes x
// 128 GEMM1 cols (acc1[8]=32 AGPR) and 16 nodes x 64 GEMM2 cols (acc2[4]=16).
// Total ~118 regs -> 4 waves/EU. Full z stage; LN = 2-wave LDS partials.
__global__ __launch_bounds__(256) void k_final(
    const unsigned int* __restrict__ aggb,
    const float* __restrict__ bns, const float* __restrict__ bnb,
    const unsigned short* __restrict__ w1p, const float* __restrict__ b1,
    const float* __restrict__ lng, const float* __restrict__ lnb,
    const unsigned short* __restrict__ w2p, const float* __restrict__ b2,
    float* __restrict__ out)
{
    __shared__ unsigned int s_z[32 * 260];   // 33280 B; t matrix aliases below
    __shared__ float s_lng[256], s_lnb[256];
    __shared__ float s_ps[2][32], s_pq[2][32];
    __shared__ float s_mu[32], s_iv[32];
    unsigned short* s_ts = reinterpret_cast<unsigned short*>(s_z);  // [32][264]

    const int tid = threadIdx.x;
    const int w = tid >> 6, lane = tid & 63, l15 = lane & 15, g = lane >> 4;
    const int ng = w & 1, ch = w >> 1;
    const int n0 = blockIdx.x * 32;

    s_lng[tid] = lng[tid];
    s_lnb[tid] = lnb[tid];

    // stage z = bf16(relu(agg*scale+shift)); thread owns uint col = tid
    float2 sv = *reinterpret_cast<const float2*>(bns + 2 * tid);
    float2 bv = *reinterpret_cast<const float2*>(bnb + 2 * tid);
    #pragma unroll 8
    for (int i = 0; i < 32; ++i) {
        int ar = (n0 + i < NN) ? n0 + i : NN - 1;
        unsigned int u = aggb[(size_t)ar * 256 + tid];
        float z0 = fmaxf(fmaf(bf_lo(u), sv.x, bv.x), 0.f);
        float z1 = fmaxf(fmaf(bf_hi(u), sv.y, bv.y), 0.f);
        s_z[i * 260 + tid] = pack2(z0, z1);
    }
    __syncthreads();

    // ---------------- GEMM1: rows ng*16+l15, out tiles ch*8+j (j<8) ---------
    const unsigned int* zrow = s_z + (ng * 16 + l15) * 260;
    const int4* B1 = reinterpret_cast<const int4*>(w1p);
    f32x4 acc1[8];
    #pragma unroll
    for (int j = 0; j < 8; ++j) acc1[j] = (f32x4){0.f, 0.f, 0.f, 0.f};

    #pragma unroll 2
    for (int kk = 0; kk < 16; ++kk) {
        Frag16B a;
        a.i = *reinterpret_cast<const int4*>(zrow + kk * 16 + g * 4);
        #pragma unroll
        for (int j = 0; j < 8; ++j) {
            Frag16B b; b.i = B1[(kk * 16 + ch * 8 + j) * 64 + lane];
            acc1[j] = __builtin_amdgcn_mfma_f32_16x16x32_bf16(a.s, b.s, acc1[j], 0, 0, 0);
        }
    }
    __syncthreads();   // all z reads done before t overwrites the buffer

    // ---------------- bias + t stash + LN partials (per col-half) -----------
    float b1v[8];
    #pragma unroll
    for (int j = 0; j < 8; ++j) b1v[j] = b1[(ch * 8 + j) * 16 + l15];

    float ssum[4] = {0, 0, 0, 0}, sq[4] = {0, 0, 0, 0};
    #pragma unroll
    for (int j = 0; j < 8; ++j) {
        float bvv = b1v[j];
        #pragma unroll
        for (int r = 0; r < 4; ++r) {
            float tv = acc1[j][r] + bvv;
            ssum[r] += tv;
            sq[r] = fmaf(tv, tv, sq[r]);
            s_ts[(ng * 16 + g * 4 + r) * 264 + (ch * 8 + j) * 16 + l15] = f2bf(tv);
        }
    }
    #pragma unroll
    for (int m = 1; m < 16; m <<= 1) {
        #pragma unroll
        for (int r = 0; r < 4; ++r) {
            ssum[r] += __shfl_xor(ssum[r], m);
            sq[r]   += __shfl_xor(sq[r], m);
        }
    }
    if (l15 < 4) {
        float svv = l15 == 0 ? ssum[0] : l15 == 1 ? ssum[1] : l15 == 2 ? ssum[2] : ssum[3];
        float qv  = l15 == 0 ? sq[0]   : l15 == 1 ? sq[1]   : l15 == 2 ? sq[2]   : sq[3];
        s_ps[ch][ng * 16 + g * 4 + l15] = svv;
        s_pq[ch][ng * 16 + g * 4 + l15] = qv;
    }
    __syncthreads();

    if (tid < 32) {
        float s = s_ps[0][tid] + s_ps[1][tid];
        float q = s_pq[0][tid] + s_pq[1][tid];
        float mean = s * (1.f / 256.f);
        float var = q * (1.f / 256.f) - mean * mean;
        s_mu[tid] = mean;
        s_iv[tid] = 1.f / sqrtf(var + 1e-5f);
    }
    __syncthreads();

    // ---------------- GEMM2: K=256 over t; out tiles ch*4+j (j<4) -----------
    const float mu_m = s_mu[ng * 16 + l15];
    const float iv_m = s_iv[ng * 16 + l15];
    const int4* B2 = reinterpret_cast<const int4*>(w2p);
    const unsigned short* trow = s_ts + (ng * 16 + l15) * 264;

    f32x4 acc2[4];
    #pragma unroll
    for (int j = 0; j < 4; ++j) acc2[j] = (f32x4){0.f, 0.f, 0.f, 0.f};

    #pragma unroll 2
    for (int kk = 0; kk < 8; ++kk) {
        const int kb = kk * 32 + g * 8;
        int4 traw = *reinterpret_cast<const int4*>(trow + kb);
        const unsigned short* tu = reinterpret_cast<const unsigned short*>(&traw);
        short8 af;
        #pragma unroll
        for (int j = 0; j < 8; ++j) {
            float tv = __uint_as_float(((unsigned int)tu[j]) << 16);
            float rn = fmaxf(fmaf((tv - mu_m) * iv_m, s_lng[kb + j], s_lnb[kb + j]), 0.f);
            af[j] = (short)f2bf(rn);
        }
        #pragma unroll
        for (int j = 0; j < 4; ++j) {
            Frag16B b; b.i = B2[(kk * 8 + ch * 4 + j) * 64 + lane];
            acc2[j] = __builtin_amdgcn_mfma_f32_16x16x32_bf16(af, b.s, acc2[j], 0, 0, 0);
        }
    }

    float b2v[4];
    #pragma unroll
    for (int j = 0; j < 4; ++j) b2v[j] = b2[(ch * 4 + j) * 16 + l15];

    #pragma unroll
    for (int j = 0; j < 4; ++j) {
        #pragma unroll
        for (int r = 0; r < 4; ++r) {
            int n = n0 + ng * 16 + g * 4 + r;
            if (n < NN)
                out[(size_t)n * 128 + (ch * 4 + j) * 16 + l15] = acc2[j][r] + b2v[j];
        }
    }
}

// ---------------------------------------------------------------------------
extern "C" void kernel_launch(void* const* d_in, const int* in_sizes, int n_in,
                              void* d_out, int out_size, void* d_ws, size_t ws_size,
                              hipStream_t stream)
{
    const float* x    = (const float*)d_in[0];
    const int*   ei   = (const int*)d_in[1];
    const float* pos  = (const float*)d_in[2];
    const float* wft  = (const float*)d_in[3];
    const float* bft  = (const float*)d_in[4];
    const float* wcv  = (const float*)d_in[5];
    const float* bcv  = (const float*)d_in[6];
    const float* vfp  = (const float*)d_in[7];
    const float* vpar = (const float*)d_in[8];
    const float* bng  = (const float*)d_in[9];
    const float* bnbe = (const float*)d_in[10];
    const float* att  = (const float*)d_in[11];
    const float* w1   = (const float*)d_in[12];
    const float* b1   = (const float*)d_in[13];
    const float* lng  = (const float*)d_in[14];
    const float* lnb  = (const float*)d_in[15];
    const float* w2   = (const float*)d_in[16];
    const float* b2   = (const float*)d_in[17];
    float* out = (float*)d_out;

    float* ws = (float*)d_ws;
    size_t off = 0;
    unsigned int* msg  = (unsigned int*)(ws + off); off += (size_t)NN * 64;    // bf16 [N][128]
    unsigned int* aggb = (unsigned int*)(ws + off); off += (size_t)NN * 256;   // bf16 [N][512]
    unsigned short* w1p  = (unsigned short*)(ws + off); off += 65536;
    unsigned short* w2p  = (unsigned short*)(ws + off); off += 16384;
    unsigned short* wftp = (unsigned short*)(ws + off); off += 8192;
    unsigned short* wcvp = (unsigned short*)(ws + off); off += 8192;
    float4* pos4 = (float4*)(ws + off); off += (size_t)NN * 4;
    float* bns  = ws + off; off += 512;
    float* bnbv = ws + off; off += 512;
    float4* dde = (float4*)(ws + off); off += (size_t)EE * 4;   // {dist,dsum,s,d}
    int* srcs   = (int*)(ws + off); off += (size_t)EE;          // SoA CSR: src
    uint2* abe  = (uint2*)(ws + off); off += (size_t)EE * 2;    // SoA CSR: ab01/ab23
    int* offs   = (int*)(ws + off); off += NN + 4;
    int* loc    = (int*)(ws + off); off += NN;
    int* bsum   = (int*)(ws + off); off += 256;
    int* bofs   = (int*)(ws + off); off += 256;
    float* blockmax = ws + off; off += 3136;
    float* dmax = ws + off; off += 4;
    size_t zstart = off;
    float* bn_psum = ws + off; off += 32 * 512;
    float* bn_psq  = ws + off; off += 32 * 512;
    int* counts = (int*)(ws + off); off += NN;
    int* cursor = (int*)(ws + off); off += NN;
    size_t zend = off;

    hipMemsetAsync(ws + zstart, 0, (zend - zstart) * sizeof(float), stream);

    k_prep<<<196, 256, 0, stream>>>(w1, att, w2, wft, wcv, pos, w1p, w2p, wftp, wcvp, pos4);
    k_ft_conv<<<782, 256, 0, stream>>>(x, wftp, bft, wcvp, bcv, msg);
    k_edge_pass1<<<3125, 256, 0, stream>>>(ei, pos4, blockmax, counts, dde);
    k_scan1<<<196, 256, 0, stream>>>(counts, loc, bsum);
    k_scan2dmax<<<2, 256, 0, stream>>>(bsum, bofs, 196, blockmax, dmax, 3125);
    k_scan3<<<196, 256, 0, stream>>>(loc, bofs, offs);
    k_fill<<<3125, 256, 0, stream>>>(dde, dmax, vfp, vpar, offs, cursor, srcs, abe);
    k_agg<<<2048, 256, 0, stream>>>(offs, srcs, abe, msg, aggb, bn_psum, bn_psq);
    k_bnfin<<<2, 256, 0, stream>>>(bn_psum, bn_psq, bng, bnbe, bns, bnbv);
    k_final<<<1563, 256, 0, stream>>>(aggb, bns, bnbv, w1p, b1, lng, lnb, w2p, b2, out);
}

// Round 5
// 325.015 us; speedup vs baseline: 1.1021x; 1.0109x over previous
//
#include <hip/hip_runtime.h>
#include <hip/hip_bf16.h>

#define NN 50000
#define EE 800000

typedef short short8 __attribute__((ext_vector_type(8)));
typedef float f32x4 __attribute__((ext_vector_type(4)));

union Frag16B { short8 s; int4 i; };
union H4 { _Float16 h[4]; uint2 u; };

static __device__ __forceinline__ unsigned short f2bf(float f) {
    union { float f; unsigned u; } v; v.f = f;
    unsigned r = v.u + 0x7FFF + ((v.u >> 16) & 1);   // RNE
    return (unsigned short)(r >> 16);
}
static __device__ __forceinline__ float bf_lo(unsigned int u) {
    return __uint_as_float(u << 16);
}
static __device__ __forceinline__ float bf_hi(unsigned int u) {
    return __uint_as_float(u & 0xFFFF0000u);
}
static __device__ __forceinline__ unsigned int pack2(float a, float b) {
    return (unsigned int)f2bf(a) | ((unsigned int)f2bf(b) << 16);
}

// ---------------- prep: fragment-major bf16 weight packing + pos->float4 ----
__global__ __launch_bounds__(256) void k_prep(
    const float* __restrict__ w1,  const float* __restrict__ att,
    const float* __restrict__ w2,
    const float* __restrict__ wft, const float* __restrict__ wcv,
    const float* __restrict__ pos,
    unsigned short* __restrict__ w1p, unsigned short* __restrict__ w2p,
    unsigned short* __restrict__ wftp, unsigned short* __restrict__ wcvp,
    float4* __restrict__ pos4)
{
    int gth = blockIdx.x * 256 + threadIdx.x;
    int lane = gth & 63, l15 = lane & 15, gg = lane >> 4;
    if (gth < 16384) {                       // w1p: kk<16, t<16, fold att[col]
        int t = (gth >> 6) & 15, kk = gth >> 10;
        int row = t * 16 + l15, c0 = kk * 32 + gg * 8;
        unsigned int pk[4];
        #pragma unroll
        for (int j = 0; j < 4; ++j) {
            int c = c0 + 2 * j;
            pk[j] = pack2(w1[row * 512 + c] * att[c],
                          w1[row * 512 + c + 1] * att[c + 1]);
        }
        *reinterpret_cast<uint4*>(w1p + (size_t)gth * 8) = make_uint4(pk[0], pk[1], pk[2], pk[3]);
    }
    if (gth < 4096) {                        // w2p: kk<8, t<8
        int t = (gth >> 6) & 7, kk = gth >> 9;
        int row = t * 16 + l15, c0 = kk * 32 + gg * 8;
        unsigned int pk[4];
        #pragma unroll
        for (int j = 0; j < 4; ++j) {
            int c = c0 + 2 * j;
            pk[j] = pack2(w2[row * 256 + c], w2[row * 256 + c + 1]);
        }
        *reinterpret_cast<uint4*>(w2p + (size_t)gth * 8) = make_uint4(pk[0], pk[1], pk[2], pk[3]);
    }
    if (gth < 2048) {                        // wftp / wcvp: kk<4, t<8
        int t = (gth >> 6) & 7, kk = gth >> 9;
        int row = t * 16 + l15, c0 = kk * 32 + gg * 8;
        unsigned int pa[4], pb[4];
        #pragma unroll
        for (int j = 0; j < 4; ++j) {
            int c = c0 + 2 * j;
            pa[j] = pack2(wft[row * 128 + c], wft[row * 128 + c + 1]);
            pb[j] = pack2(wcv[row * 128 + c], wcv[row * 128 + c + 1]);
        }
        *reinterpret_cast<uint4*>(wftp + (size_t)gth * 8) = make_uint4(pa[0], pa[1], pa[2], pa[3]);
        *reinterpret_cast<uint4*>(wcvp + (size_t)gth * 8) = make_uint4(pb[0], pb[1], pb[2], pb[3]);
    }
    if (gth < NN) {                          // pos -> padded float4
        pos4[gth] = make_float4(pos[gth * 3 + 0], pos[gth * 3 + 1], pos[gth * 3 + 2], 0.f);
    }
}

// ---------------- fused node GEMMs (MFMA): msg = (relu(x WftT+bft)) WcvT + bcv
__global__ __launch_bounds__(256) void k_ft_conv(
    const float* __restrict__ x,
    const unsigned short* __restrict__ wftp, const float* __restrict__ bft,
    const unsigned short* __restrict__ wcvp, const float* __restrict__ bcv,
    unsigned int* __restrict__ msg)          // bf16 [NN][128] as uint[NN][64]
{
    __shared__ unsigned int s_x[64 * 68];    // bf16 tile (reused for out)
    __shared__ unsigned short s_h[64 * 136];
    const int tid = threadIdx.x;
    const int w = tid >> 6, lane = tid & 63, l15 = lane & 15, g = lane >> 4;
    const int n0 = blockIdx.x * 64;

    #pragma unroll
    for (int i = 0; i < 8; ++i) {
        int lin = tid + i * 256;
        int row = lin >> 5, c4 = lin & 31;
        int ar = (n0 + row < NN) ? n0 + row : NN - 1;
        float4 v = *reinterpret_cast<const float4*>(x + (size_t)ar * 128 + c4 * 4);
        s_x[row * 68 + c4 * 2]     = pack2(v.x, v.y);
        s_x[row * 68 + c4 * 2 + 1] = pack2(v.z, v.w);
    }
    __syncthreads();

    float bftv[8], bcvv[8];
    #pragma unroll
    for (int t = 0; t < 8; ++t) { bftv[t] = bft[t * 16 + l15]; bcvv[t] = bcv[t * 16 + l15]; }

    const int4* Bf = reinterpret_cast<const int4*>(wftp);
    f32x4 acc[8];
    #pragma unroll
    for (int t = 0; t < 8; ++t) acc[t] = (f32x4){0.f, 0.f, 0.f, 0.f};
    #pragma unroll
    for (int kk = 0; kk < 4; ++kk) {
        Frag16B a;
        a.i = *reinterpret_cast<const int4*>(&s_x[(w * 16 + l15) * 68 + kk * 16 + g * 4]);
        #pragma unroll
        for (int t = 0; t < 8; ++t) {
            Frag16B b; b.i = Bf[(kk * 8 + t) * 64 + lane];
            acc[t] = __builtin_amdgcn_mfma_f32_16x16x32_bf16(a.s, b.s, acc[t], 0, 0, 0);
        }
    }
    #pragma unroll
    for (int t = 0; t < 8; ++t)
        #pragma unroll
        for (int r = 0; r < 4; ++r)
            s_h[(w * 16 + g * 4 + r) * 136 + t * 16 + l15] =
                f2bf(fmaxf(acc[t][r] + bftv[t], 0.f));
    __syncthreads();

    const int4* Bc = reinterpret_cast<const int4*>(wcvp);
    #pragma unroll
    for (int t = 0; t < 8; ++t) acc[t] = (f32x4){0.f, 0.f, 0.f, 0.f};
    #pragma unroll
    for (int kk = 0; kk < 4; ++kk) {
        Frag16B a;
        a.i = *reinterpret_cast<const int4*>(&s_h[(w * 16 + l15) * 136 + kk * 32 + g * 8]);
        #pragma unroll
        for (int t = 0; t < 8; ++t) {
            Frag16B b; b.i = Bc[(kk * 8 + t) * 64 + lane];
            acc[t] = __builtin_amdgcn_mfma_f32_16x16x32_bf16(a.s, b.s, acc[t], 0, 0, 0);
        }
    }
    unsigned short* s_o = reinterpret_cast<unsigned short*>(s_x);
    #pragma unroll
    for (int t = 0; t < 8; ++t)
        #pragma unroll
        for (int r = 0; r < 4; ++r)
            s_o[(w * 16 + g * 4 + r) * 136 + t * 16 + l15] = f2bf(acc[t][r] + bcvv[t]);
    __syncthreads();
    #pragma unroll
    for (int i = 0; i < 8; ++i) {
        int lin = tid + i * 256;
        int row = lin >> 5, cu2 = lin & 31;
        if (n0 + row < NN) {
            uint2 v;
            v.x = s_x[row * 68 + cu2 * 2];
            v.y = s_x[row * 68 + cu2 * 2 + 1];
            *reinterpret_cast<uint2*>(msg + (size_t)(n0 + row) * 64 + cu2 * 2) = v;
        }
    }
}

// ---------------- edge pass 1: {dist,dsum,s,d} record + degree + block max --
__global__ __launch_bounds__(256) void k_edge_pass1(
    const int* __restrict__ ei, const float4* __restrict__ pos4,
    float* __restrict__ blockmax, int* __restrict__ counts,
    float4* __restrict__ dde)
{
    __shared__ float smax[4];
    int e = blockIdx.x * 256 + threadIdx.x;       // grid covers EE exactly
    int s = ei[e], d = ei[EE + e];
    float4 ps = pos4[s], pd = pos4[d];
    float dx = ps.x - pd.x, dy = ps.y - pd.y, dz = ps.z - pd.z;
    float dist = sqrtf(dx * dx + dy * dy + dz * dz);
    float rinv = 1.f / (dist + 1e-8f);
    dde[e] = make_float4(dist, (dx + dy + dz) * rinv,
                         __int_as_float(s), __int_as_float(d));
    atomicAdd(&counts[d], 1);

    float m = dist;
    #pragma unroll
    for (int o = 32; o >= 1; o >>= 1)
        m = fmaxf(m, __shfl_xor(m, o));
    if ((threadIdx.x & 63) == 0) smax[threadIdx.x >> 6] = m;
    __syncthreads();
    if (threadIdx.x == 0)
        blockmax[blockIdx.x] = fmaxf(fmaxf(smax[0], smax[1]), fmaxf(smax[2], smax[3]));
}

// ---------------- 3-kernel exclusive scan over counts -----------------------
__global__ __launch_bounds__(256) void k_scan1(const int* __restrict__ counts,
    int* __restrict__ loc, int* __restrict__ bsum)
{
    __shared__ int sd[256];
    int i = blockIdx.x * 256 + threadIdx.x;
    int v = (i < NN) ? counts[i] : 0;
    sd[threadIdx.x] = v;
    __syncthreads();
    for (int ofs = 1; ofs < 256; ofs <<= 1) {
        int t = (threadIdx.x >= ofs) ? sd[threadIdx.x - ofs] : 0;
        __syncthreads();
        sd[threadIdx.x] += t;
        __syncthreads();
    }
    int incl = sd[threadIdx.x];
    if (i < NN) loc[i] = incl - v;
    if (threadIdx.x == 255) bsum[blockIdx.x] = incl;
}

// block 0: exclusive scan of bsum; block 1: dmax reduce over blockmax
__global__ __launch_bounds__(256) void k_scan2dmax(const int* __restrict__ bsum,
    int* __restrict__ bofs, int nb,
    const float* __restrict__ blockmax, float* __restrict__ dmax, int nmb)
{
    if (blockIdx.x == 0) {
        __shared__ int sd[256];
        int v = (threadIdx.x < nb) ? bsum[threadIdx.x] : 0;
        sd[threadIdx.x] = v;
        __syncthreads();
        for (int ofs = 1; ofs < 256; ofs <<= 1) {
            int t = (threadIdx.x >= ofs) ? sd[threadIdx.x - ofs] : 0;
            __syncthreads();
            sd[threadIdx.x] += t;
            __syncthreads();
        }
        bofs[threadIdx.x] = sd[threadIdx.x] - v;
    } else {
        __shared__ float smax[4];
        float m = 0.f;
        for (int i = threadIdx.x; i < nmb; i += 256) m = fmaxf(m, blockmax[i]);
        #pragma unroll
        for (int o = 32; o >= 1; o >>= 1)
            m = fmaxf(m, __shfl_xor(m, o));
        if ((threadIdx.x & 63) == 0) smax[threadIdx.x >> 6] = m;
        __syncthreads();
        if (threadIdx.x == 0)
            dmax[0] = fmaxf(fmaxf(smax[0], smax[1]), fmaxf(smax[2], smax[3]));
    }
}

__global__ __launch_bounds__(256) void k_scan3(const int* __restrict__ loc,
    const int* __restrict__ bofs, int* __restrict__ offs)
{
    int i = blockIdx.x * 256 + threadIdx.x;
    if (i < NN) offs[i] = loc[i] + bofs[blockIdx.x];
    if (i == 0) offs[NN] = EE;
}

// ---------------- edge pass 2: ab factors + SoA CSR record ------------------
__global__ __launch_bounds__(256) void k_fill(
    const float4* __restrict__ dde,
    const float* __restrict__ dmaxp,
    const float* __restrict__ vfp, const float* __restrict__ vpar,
    const int* __restrict__ offs, int* __restrict__ cursor,
    int* __restrict__ srcs, uint2* __restrict__ abe)
{
    int e = blockIdx.x * 256 + threadIdx.x;       // grid covers EE exactly
    float4 v4 = dde[e];
    int s = __float_as_int(v4.z), d = __float_as_int(v4.w);
    float r = v4.x / dmaxp[0];
    float dsum = v4.y;
    float vf = vfp[0];
    H4 p;
    #pragma unroll
    for (int k = 0; k < 4; ++k) {
        float v = vf * fminf(r, vpar[k]);
        p.h[k] = (_Float16)(sqrtf(1.f - v * v + 1e-8f) / (1.f + v * dsum));
    }
    int slot = offs[d] + atomicAdd(&cursor[d], 1);
    srcs[slot] = s;
    abe[slot] = p.u;
}

// ---------------- aggregation + fused BN partial stats ----------------------
// Full wave per edge (lane owns msg uint col = lane). Grid-stride: 2048
// blocks = 32 waves/CU resident, 8192 waves cover 50000 nodes (~6 each).
// SoA edge records via wave-uniform indices (SGPR path); width-8 batches
// with zeroed tail coefficients — no serial tail.
__global__ __launch_bounds__(256) void k_agg(
    const int* __restrict__ offs, const int* __restrict__ srcs,
    const uint2* __restrict__ abe, const unsigned int* __restrict__ msg,
    unsigned int* __restrict__ aggb,         // bf16 [NN][512] as uint[NN][256]
    float* __restrict__ bn_psum, float* __restrict__ bn_psq)
{
    __shared__ float s_bn[4 * 1024];         // [wave][16 vals][64 lanes]
    const int tid = threadIdx.x;
    const int lane = tid & 63;
    const int w = __builtin_amdgcn_readfirstlane(tid >> 6);
    const int gw = (blockIdx.x << 2) | w;    // 0..8191

    float ps0 = 0, ps1 = 0, ps2 = 0, ps3 = 0, ps4 = 0, ps5 = 0, ps6 = 0, ps7 = 0;
    float pq0 = 0, pq1 = 0, pq2 = 0, pq3 = 0, pq4 = 0, pq5 = 0, pq6 = 0, pq7 = 0;

    for (int n = gw; n < NN; n += 8192) {
        int st = __builtin_amdgcn_readfirstlane(offs[n]);
        int en = __builtin_amdgcn_readfirstlane(offs[n + 1]);
        float a00 = 0, a10 = 0, a20 = 0, a30 = 0, a01 = 0, a11 = 0, a21 = 0, a31 = 0;

        for (int e = st; e < en; e += 8) {
            int idx[8];
            unsigned int uu[8];
            #pragma unroll
            for (int j = 0; j < 8; ++j) {
                int ee = e + j;
                idx[j] = (ee < en) ? ee : en - 1;       // wave-uniform clamp
            }
            #pragma unroll
            for (int j = 0; j < 8; ++j)
                uu[j] = msg[(size_t)srcs[idx[j]] * 64 + lane];
            #pragma unroll
            for (int j = 0; j < 8; ++j) {
                uint2 a = abe[idx[j]];
                bool valid = (e + j) < en;              // wave-uniform
                a.x = valid ? a.x : 0u;
                a.y = valid ? a.y : 0u;
                H4 p; p.u = a;
                float m0 = bf_lo(uu[j]), m1 = bf_hi(uu[j]);
                a00 = fmaf((float)p.h[0], m0, a00); a01 = fmaf((float)p.h[0], m1, a01);
                a10 = fmaf((float)p.h[1], m0, a10); a11 = fmaf((float)p.h[1], m1, a11);
                a20 = fmaf((float)p.h[2], m0, a20); a21 = fmaf((float)p.h[2], m1, a21);
                a30 = fmaf((float)p.h[3], m0, a30); a31 = fmaf((float)p.h[3], m1, a31);
            }
        }

        unsigned int* o = aggb + (size_t)n * 256 + lane;   // col c = k*128 + h
        o[0]   = pack2(a00, a01);
        o[64]  = pack2(a10, a11);
        o[128] = pack2(a20, a21);
        o[192] = pack2(a30, a31);

        ps0 += a00; pq0 = fmaf(a00, a00, pq0);
        ps1 += a01; pq1 = fmaf(a01, a01, pq1);
        ps2 += a10; pq2 = fmaf(a10, a10, pq2);
        ps3 += a11; pq3 = fmaf(a11, a11, pq3);
        ps4 += a20; pq4 = fmaf(a20, a20, pq4);
        ps5 += a21; pq5 = fmaf(a21, a21, pq5);
        ps6 += a30; pq6 = fmaf(a30, a30, pq6);
        ps7 += a31; pq7 = fmaf(a31, a31, pq7);
    }

    // per-wave partials -> LDS
    float* sw = s_bn + w * 1024 + lane;
    sw[0 * 64] = ps0; sw[1 * 64] = ps1; sw[2 * 64] = ps2; sw[3 * 64] = ps3;
    sw[4 * 64] = ps4; sw[5 * 64] = ps5; sw[6 * 64] = ps6; sw[7 * 64] = ps7;
    sw[8 * 64] = pq0; sw[9 * 64] = pq1; sw[10 * 64] = pq2; sw[11 * 64] = pq3;
    sw[12 * 64] = pq4; sw[13 * 64] = pq5; sw[14 * 64] = pq6; sw[15 * 64] = pq7;
    __syncthreads();

    // cross-wave reduce + one atomic per entry (1024 entries / 256 threads)
    int part = (blockIdx.x & 31) * 512;
    #pragma unroll
    for (int k = 0; k < 4; ++k) {
        int idx = tid + k * 256;                 // 0..1023
        float s = s_bn[idx] + s_bn[1024 + idx] + s_bn[2048 + idx] + s_bn[3072 + idx];
        int v = idx >> 6, ln = idx & 63;
        int col = ((v & 7) >> 1) * 128 + 2 * ln + (v & 1);
        if (v < 8) atomicAdd(&bn_psum[part + col], s);
        else       atomicAdd(&bn_psq[part + col], s);
    }
}

__global__ __launch_bounds__(256) void k_bnfin(const float* __restrict__ bn_psum,
    const float* __restrict__ bn_psq, const float* __restrict__ bng,
    const float* __restrict__ bnbeta, float* __restrict__ bns, float* __restrict__ bnbv)
{
    int c = blockIdx.x * 256 + threadIdx.x;
    if (c >= 512) return;
    float s = 0.f, q = 0.f;
    #pragma unroll 8
    for (int p = 0; p < 32; ++p) {
        s += bn_psum[p * 512 + c];
        q += bn_psq[p * 512 + c];
    }
    float mean = s * (1.f / NN);
    float var = q * (1.f / NN) - mean * mean;
    float sc = bng[c] / sqrtf(var + 1e-5f);
    bns[c] = sc;
    bnbv[c] = bnbeta[c] - mean * sc;
}

// ---------------- final fused MFMA: 64-node tile, 4x B-frag register reuse --
// Block = 4 waves, 64 nodes, grid 782. Wave w owns ALL 4 row-tiles (64 rows)
// x its col-quarter: GEMM1 cols [w*64,+64) (4 j-tiles), GEMM2 cols [w*32,+32)
// (2 j-tiles). Per kk: 4 B-frags loaded once from L2, each reused by 4 MFMAs
// (one per row-tile) -> B1 traffic 800MB -> 200MB (the R4 bottleneck: MFMA
// operand streaming from L2 at 2.5 waves/SIMD). z staged once in LDS
// (64x260 uints, 66.5KB); t (64x264 shorts, 33.8KB) overlays z after GEMM1.
// LDS ~71KB -> 2 blocks/CU; launch_bounds(256,2) allows acc1[16]=64 regs.
__global__ __launch_bounds__(256, 2) void k_final(
    const unsigned int* __restrict__ aggb,
    const float* __restrict__ bns, const float* __restrict__ bnb,
    const unsigned short* __restrict__ w1p, const float* __restrict__ b1,
    const float* __restrict__ lng, const float* __restrict__ lnb,
    const unsigned short* __restrict__ w2p, const float* __restrict__ b2,
    float* __restrict__ out)
{
    __shared__ unsigned int s_z[64 * 260];   // 66560 B; t matrix aliases below
    __shared__ float s_lng[256], s_lnb[256];
    __shared__ float s_ps[4][64], s_pq[4][64];
    __shared__ float s_mu[64], s_iv[64];
    unsigned short* s_ts = reinterpret_cast<unsigned short*>(s_z);  // [64][264]

    const int tid = threadIdx.x;
    const int w = tid >> 6, lane = tid & 63, l15 = lane & 15, g = lane >> 4;
    const int n0 = blockIdx.x * 64;

    s_lng[tid] = lng[tid];
    s_lnb[tid] = lnb[tid];

    // stage z = bf16(relu(agg*scale+shift)); thread owns uint col = tid
    float2 sv = *reinterpret_cast<const float2*>(bns + 2 * tid);
    float2 bv = *reinterpret_cast<const float2*>(bnb + 2 * tid);
    #pragma unroll 8
    for (int i = 0; i < 64; ++i) {
        int ar = (n0 + i < NN) ? n0 + i : NN - 1;
        unsigned int u = aggb[(size_t)ar * 256 + tid];
        float z0 = fmaxf(fmaf(bf_lo(u), sv.x, bv.x), 0.f);
        float z1 = fmaxf(fmaf(bf_hi(u), sv.y, bv.y), 0.f);
        s_z[i * 260 + tid] = pack2(z0, z1);
    }
    __syncthreads();

    // ---------------- GEMM1: 4 row-tiles x 4 j-tiles, B reused x4 -----------
    const int4* B1 = reinterpret_cast<const int4*>(w1p);
    f32x4 acc1[16];                          // [rt*4 + j]
    #pragma unroll
    for (int i = 0; i < 16; ++i) acc1[i] = (f32x4){0.f, 0.f, 0.f, 0.f};

    #pragma unroll 2
    for (int kk = 0; kk < 16; ++kk) {
        Frag16B b[4];
        #pragma unroll
        for (int j = 0; j < 4; ++j)
            b[j].i = B1[(kk * 16 + w * 4 + j) * 64 + lane];
        Frag16B a[4];
        #pragma unroll
        for (int rt = 0; rt < 4; ++rt)
            a[rt].i = *reinterpret_cast<const int4*>(
                &s_z[(rt * 16 + l15) * 260 + kk * 16 + g * 4]);
        #pragma unroll
        for (int rt = 0; rt < 4; ++rt)
            #pragma unroll
            for (int j = 0; j < 4; ++j)
                acc1[rt * 4 + j] = __builtin_amdgcn_mfma_f32_16x16x32_bf16(
                    a[rt].s, b[j].s, acc1[rt * 4 + j], 0, 0, 0);
    }
    __syncthreads();   // all z reads done before t overwrites the buffer

    // ---------------- bias + t stash + LN partials (per col-quarter) --------
    float b1v[4];
    #pragma unroll
    for (int j = 0; j < 4; ++j) b1v[j] = b1[(w * 4 + j) * 16 + l15];

    float ssum[16], ssq[16];                 // [rt*4 + r]
    #pragma unroll
    for (int i = 0; i < 16; ++i) { ssum[i] = 0.f; ssq[i] = 0.f; }
    #pragma unroll
    for (int rt = 0; rt < 4; ++rt)
        #pragma unroll
        for (int j = 0; j < 4; ++j) {
            float bvv = b1v[j];
            #pragma unroll
            for (int r = 0; r < 4; ++r) {
                float tv = acc1[rt * 4 + j][r] + bvv;
                ssum[rt * 4 + r] += tv;
                ssq[rt * 4 + r] = fmaf(tv, tv, ssq[rt * 4 + r]);
                s_ts[(rt * 16 + g * 4 + r) * 264 + (w * 4 + j) * 16 + l15] = f2bf(tv);
            }
        }
    #pragma unroll
    for (int m = 1; m < 16; m <<= 1) {
        #pragma unroll
        for (int i = 0; i < 16; ++i) {
            ssum[i] += __shfl_xor(ssum[i], m);
            ssq[i]  += __shfl_xor(ssq[i], m);
        }
    }
    if (l15 == 0) {
        #pragma unroll
        for (int rt = 0; rt < 4; ++rt)
            #pragma unroll
            for (int r = 0; r < 4; ++r) {
                s_ps[w][rt * 16 + g * 4 + r] = ssum[rt * 4 + r];
                s_pq[w][rt * 16 + g * 4 + r] = ssq[rt * 4 + r];
            }
    }
    __syncthreads();

    if (tid < 64) {
        float s = s_ps[0][tid] + s_ps[1][tid] + s_ps[2][tid] + s_ps[3][tid];
        float q = s_pq[0][tid] + s_pq[1][tid] + s_pq[2][tid] + s_pq[3][tid];
        float mean = s * (1.f / 256.f);
        float var = q * (1.f / 256.f) - mean * mean;
        s_mu[tid] = mean;
        s_iv[tid] = 1.f / sqrtf(var + 1e-5f);
    }
    __syncthreads();

    // ---------------- GEMM2: K=256 over t; 4 row-tiles x 2 j-tiles ----------
    float mu_m[4], iv_m[4];
    #pragma unroll
    for (int rt = 0; rt < 4; ++rt) {
        mu_m[rt] = s_mu[rt * 16 + l15];
        iv_m[rt] = s_iv[rt * 16 + l15];
    }
    const int4* B2 = reinterpret_cast<const int4*>(w2p);

    f32x4 acc2[8];                           // [rt*2 + j]
    #pragma unroll
    for (int i = 0; i < 8; ++i) acc2[i] = (f32x4){0.f, 0.f, 0.f, 0.f};

    #pragma unroll 2
    for (int kk = 0; kk < 8; ++kk) {
        const int kb = kk * 32 + g * 8;
        Frag16B b[2];
        #pragma unroll
        for (int j = 0; j < 2; ++j)
            b[j].i = B2[(kk * 8 + w * 2 + j) * 64 + lane];
        float lg[8], lb[8];
        #pragma unroll
        for (int jj = 0; jj < 8; ++jj) { lg[jj] = s_lng[kb + jj]; lb[jj] = s_lnb[kb + jj]; }
        #pragma unroll
        for (int rt = 0; rt < 4; ++rt) {
            int4 traw = *reinterpret_cast<const int4*>(
                &s_ts[(rt * 16 + l15) * 264 + kb]);
            const unsigned short* tu = reinterpret_cast<const unsigned short*>(&traw);
            short8 af;
            #pragma unroll
            for (int jj = 0; jj < 8; ++jj) {
                float tv = __uint_as_float(((unsigned int)tu[jj]) << 16);
                float rn = fmaxf(fmaf((tv - mu_m[rt]) * iv_m[rt], lg[jj], lb[jj]), 0.f);
                af[jj] = (short)f2bf(rn);
            }
            #pragma unroll
            for (int j = 0; j < 2; ++j)
                acc2[rt * 2 + j] = __builtin_amdgcn_mfma_f32_16x16x32_bf16(
                    af, b[j].s, acc2[rt * 2 + j], 0, 0, 0);
        }
    }

    float b2v[2];
    #pragma unroll
    for (int j = 0; j < 2; ++j) b2v[j] = b2[(w * 2 + j) * 16 + l15];

    #pragma unroll
    for (int rt = 0; rt < 4; ++rt)
        #pragma unroll
        for (int j = 0; j < 2; ++j)
            #pragma unroll
            for (int r = 0; r < 4; ++r) {
                int n = n0 + rt * 16 + g * 4 + r;
                if (n < NN)
                    out[(size_t)n * 128 + (w * 2 + j) * 16 + l15] = acc2[rt * 2 + j][r] + b2v[j];
            }
}

// ---------------------------------------------------------------------------
extern "C" void kernel_launch(void* const* d_in, const int* in_sizes, int n_in,
                              void* d_out, int out_size, void* d_ws, size_t ws_size,
                              hipStream_t stream)
{
    const float* x    = (const float*)d_in[0];
    const int*   ei   = (const int*)d_in[1];
    const float* pos  = (const float*)d_in[2];
    const float* wft  = (const float*)d_in[3];
    const float* bft  = (const float*)d_in[4];
    const float* wcv  = (const float*)d_in[5];
    const float* bcv  = (const float*)d_in[6];
    const float* vfp  = (const float*)d_in[7];
    const float* vpar = (const float*)d_in[8];
    const float* bng  = (const float*)d_in[9];
    const float* bnbe = (const float*)d_in[10];
    const float* att  = (const float*)d_in[11];
    const float* w1   = (const float*)d_in[12];
    const float* b1   = (const float*)d_in[13];
    const float* lng  = (const float*)d_in[14];
    const float* lnb  = (const float*)d_in[15];
    const float* w2   = (const float*)d_in[16];
    const float* b2   = (const float*)d_in[17];
    float* out = (float*)d_out;

    float* ws = (float*)d_ws;
    size_t off = 0;
    unsigned int* msg  = (unsigned int*)(ws + off); off += (size_t)NN * 64;    // bf16 [N][128]
    unsigned int* aggb = (unsigned int*)(ws + off); off += (size_t)NN * 256;   // bf16 [N][512]
    unsigned short* w1p  = (unsigned short*)(ws + off); off += 65536;
    unsigned short* w2p  = (unsigned short*)(ws + off); off += 16384;
    unsigned short* wftp = (unsigned short*)(ws + off); off += 8192;
    unsigned short* wcvp = (unsigned short*)(ws + off); off += 8192;
    float4* pos4 = (float4*)(ws + off); off += (size_t)NN * 4;
    float* bns  = ws + off; off += 512;
    float* bnbv = ws + off; off += 512;
    float4* dde = (float4*)(ws + off); off += (size_t)EE * 4;   // {dist,dsum,s,d}
    int* srcs   = (int*)(ws + off); off += (size_t)EE;          // SoA CSR: src
    uint2* abe  = (uint2*)(ws + off); off += (size_t)EE * 2;    // SoA CSR: ab01/ab23
    int* offs   = (int*)(ws + off); off += NN + 4;
    int* loc    = (int*)(ws + off); off += NN;
    int* bsum   = (int*)(ws + off); off += 256;
    int* bofs   = (int*)(ws + off); off += 256;
    float* blockmax = ws + off; off += 3136;
    float* dmax = ws + off; off += 4;
    size_t zstart = off;
    float* bn_psum = ws + off; off += 32 * 512;
    float* bn_psq  = ws + off; off += 32 * 512;
    int* counts = (int*)(ws + off); off += NN;
    int* cursor = (int*)(ws + off); off += NN;
    size_t zend = off;

    hipMemsetAsync(ws + zstart, 0, (zend - zstart) * sizeof(float), stream);

    k_prep<<<196, 256, 0, stream>>>(w1, att, w2, wft, wcv, pos, w1p, w2p, wftp, wcvp, pos4);
    k_ft_conv<<<782, 256, 0, stream>>>(x, wftp, bft, wcvp, bcv, msg);
    k_edge_pass1<<<3125, 256, 0, stream>>>(ei, pos4, blockmax, counts, dde);
    k_scan1<<<196, 256, 0, stream>>>(counts, loc, bsum);
    k_scan2dmax<<<2, 256, 0, stream>>>(bsum, bofs, 196, blockmax, dmax, 3125);
    k_scan3<<<196, 256, 0, stream>>>(loc, bofs, offs);
    k_fill<<<3125, 256, 0, stream>>>(dde, dmax, vfp, vpar, offs, cursor, srcs, abe);
    k_agg<<<2048, 256, 0, stream>>>(offs, srcs, abe, msg, aggb, bn_psum, bn_psq);
    k_bnfin<<<2, 256, 0, stream>>>(bn_psum, bn_psq, bng, bnbe, bns, bnbv);
    k_final<<<782, 256, 0, stream>>>(aggb, bns, bnbv, w1p, b1, lng, lnb, w2p, b2, out);
}

// Round 7
// 319.175 us; speedup vs baseline: 1.1222x; 1.0183x over previous
//
#include <hip/hip_runtime.h>
#include <hip/hip_bf16.h>

#define NN 50000
#define EE 800000

typedef short short8 __attribute__((ext_vector_type(8)));
typedef float f32x4 __attribute__((ext_vector_type(4)));

union Frag16B { short8 s; int4 i; };
union H4 { _Float16 h[4]; uint2 u; };

static __device__ __forceinline__ unsigned short f2bf(float f) {
    union { float f; unsigned u; } v; v.f = f;
    unsigned r = v.u + 0x7FFF + ((v.u >> 16) & 1);   // RNE
    return (unsigned short)(r >> 16);
}
static __device__ __forceinline__ float bf_lo(unsigned int u) {
    return __uint_as_float(u << 16);
}
static __device__ __forceinline__ float bf_hi(unsigned int u) {
    return __uint_as_float(u & 0xFFFF0000u);
}
static __device__ __forceinline__ unsigned int pack2(float a, float b) {
    return (unsigned int)f2bf(a) | ((unsigned int)f2bf(b) << 16);
}

// ---------------- prep: fragment-major bf16 weight packing + pos->float4 ----
__global__ __launch_bounds__(256) void k_prep(
    const float* __restrict__ w1,  const float* __restrict__ att,
    const float* __restrict__ w2,
    const float* __restrict__ wft, const float* __restrict__ wcv,
    const float* __restrict__ pos,
    unsigned short* __restrict__ w1p, unsigned short* __restrict__ w2p,
    unsigned short* __restrict__ wftp, unsigned short* __restrict__ wcvp,
    float4* __restrict__ pos4)
{
    int gth = blockIdx.x * 256 + threadIdx.x;
    int lane = gth & 63, l15 = lane & 15, gg = lane >> 4;
    if (gth < 16384) {                       // w1p: kk<16, t<16, fold att[col]
        int t = (gth >> 6) & 15, kk = gth >> 10;
        int row = t * 16 + l15, c0 = kk * 32 + gg * 8;
        unsigned int pk[4];
        #pragma unroll
        for (int j = 0; j < 4; ++j) {
            int c = c0 + 2 * j;
            pk[j] = pack2(w1[row * 512 + c] * att[c],
                          w1[row * 512 + c + 1] * att[c + 1]);
        }
        *reinterpret_cast<uint4*>(w1p + (size_t)gth * 8) = make_uint4(pk[0], pk[1], pk[2], pk[3]);
    }
    if (gth < 4096) {                        // w2p: kk<8, t<8
        int t = (gth >> 6) & 7, kk = gth >> 9;
        int row = t * 16 + l15, c0 = kk * 32 + gg * 8;
        unsigned int pk[4];
        #pragma unroll
        for (int j = 0; j < 4; ++j) {
            int c = c0 + 2 * j;
            pk[j] = pack2(w2[row * 256 + c], w2[row * 256 + c + 1]);
        }
        *reinterpret_cast<uint4*>(w2p + (size_t)gth * 8) = make_uint4(pk[0], pk[1], pk[2], pk[3]);
    }
    if (gth < 2048) {                        // wftp / wcvp: kk<4, t<8
        int t = (gth >> 6) & 7, kk = gth >> 9;
        int row = t * 16 + l15, c0 = kk * 32 + gg * 8;
        unsigned int pa[4], pb[4];
        #pragma unroll
        for (int j = 0; j < 4; ++j) {
            int c = c0 + 2 * j;
            pa[j] = pack2(wft[row * 128 + c], wft[row * 128 + c + 1]);
            pb[j] = pack2(wcv[row * 128 + c], wcv[row * 128 + c + 1]);
        }
        *reinterpret_cast<uint4*>(wftp + (size_t)gth * 8) = make_uint4(pa[0], pa[1], pa[2], pa[3]);
        *reinterpret_cast<uint4*>(wcvp + (size_t)gth * 8) = make_uint4(pb[0], pb[1], pb[2], pb[3]);
    }
    if (gth < NN) {                          // pos -> padded float4
        pos4[gth] = make_float4(pos[gth * 3 + 0], pos[gth * 3 + 1], pos[gth * 3 + 2], 0.f);
    }
}

// ---------------- fused node GEMMs (MFMA): msg = (relu(x WftT+bft)) WcvT + bcv
__global__ __launch_bounds__(256) void k_ft_conv(
    const float* __restrict__ x,
    const unsigned short* __restrict__ wftp, const float* __restrict__ bft,
    const unsigned short* __restrict__ wcvp, const float* __restrict__ bcv,
    unsigned int* __restrict__ msg)          // bf16 [NN][128] as uint[NN][64]
{
    __shared__ unsigned int s_x[64 * 68];    // bf16 tile (reused for out)
    __shared__ unsigned short s_h[64 * 136];
    const int tid = threadIdx.x;
    const int w = tid >> 6, lane = tid & 63, l15 = lane & 15, g = lane >> 4;
    const int n0 = blockIdx.x * 64;

    #pragma unroll
    for (int i = 0; i < 8; ++i) {
        int lin = tid + i * 256;
        int row = lin >> 5, c4 = lin & 31;
        int ar = (n0 + row < NN) ? n0 + row : NN - 1;
        float4 v = *reinterpret_cast<const float4*>(x + (size_t)ar * 128 + c4 * 4);
        s_x[row * 68 + c4 * 2]     = pack2(v.x, v.y);
        s_x[row * 68 + c4 * 2 + 1] = pack2(v.z, v.w);
    }
    __syncthreads();

    float bftv[8], bcvv[8];
    #pragma unroll
    for (int t = 0; t < 8; ++t) { bftv[t] = bft[t * 16 + l15]; bcvv[t] = bcv[t * 16 + l15]; }

    const int4* Bf = reinterpret_cast<const int4*>(wftp);
    f32x4 acc[8];
    #pragma unroll
    for (int t = 0; t < 8; ++t) acc[t] = (f32x4){0.f, 0.f, 0.f, 0.f};
    #pragma unroll
    for (int kk = 0; kk < 4; ++kk) {
        Frag16B a;
        a.i = *reinterpret_cast<const int4*>(&s_x[(w * 16 + l15) * 68 + kk * 16 + g * 4]);
        #pragma unroll
        for (int t = 0; t < 8; ++t) {
            Frag16B b; b.i = Bf[(kk * 8 + t) * 64 + lane];
            acc[t] = __builtin_amdgcn_mfma_f32_16x16x32_bf16(a.s, b.s, acc[t], 0, 0, 0);
        }
    }
    #pragma unroll
    for (int t = 0; t < 8; ++t)
        #pragma unroll
        for (int r = 0; r < 4; ++r)
            s_h[(w * 16 + g * 4 + r) * 136 + t * 16 + l15] =
                f2bf(fmaxf(acc[t][r] + bftv[t], 0.f));
    __syncthreads();

    const int4* Bc = reinterpret_cast<const int4*>(wcvp);
    #pragma unroll
    for (int t = 0; t < 8; ++t) acc[t] = (f32x4){0.f, 0.f, 0.f, 0.f};
    #pragma unroll
    for (int kk = 0; kk < 4; ++kk) {
        Frag16B a;
        a.i = *reinterpret_cast<const int4*>(&s_h[(w * 16 + l15) * 136 + kk * 32 + g * 8]);
        #pragma unroll
        for (int t = 0; t < 8; ++t) {
            Frag16B b; b.i = Bc[(kk * 8 + t) * 64 + lane];
            acc[t] = __builtin_amdgcn_mfma_f32_16x16x32_bf16(a.s, b.s, acc[t], 0, 0, 0);
        }
    }
    unsigned short* s_o = reinterpret_cast<unsigned short*>(s_x);
    #pragma unroll
    for (int t = 0; t < 8; ++t)
        #pragma unroll
        for (int r = 0; r < 4; ++r)
            s_o[(w * 16 + g * 4 + r) * 136 + t * 16 + l15] = f2bf(acc[t][r] + bcvv[t]);
    __syncthreads();
    #pragma unroll
    for (int i = 0; i < 8; ++i) {
        int lin = tid + i * 256;
        int row = lin >> 5, cu2 = lin & 31;
        if (n0 + row < NN) {
            uint2 v;
            v.x = s_x[row * 68 + cu2 * 2];
            v.y = s_x[row * 68 + cu2 * 2 + 1];
            *reinterpret_cast<uint2*>(msg + (size_t)(n0 + row) * 64 + cu2 * 2) = v;
        }
    }
}

// ---------------- edge pass 1: degree + block max only (no dde record) ------
__global__ __launch_bounds__(256) void k_edge_pass1(
    const int* __restrict__ ei, const float4* __restrict__ pos4,
    float* __restrict__ blockmax, int* __restrict__ counts)
{
    __shared__ float smax[4];
    int e = blockIdx.x * 256 + threadIdx.x;       // grid covers EE exactly
    int s = ei[e], d = ei[EE + e];
    float4 ps = pos4[s], pd = pos4[d];
    float dx = ps.x - pd.x, dy = ps.y - pd.y, dz = ps.z - pd.z;
    float dist = sqrtf(dx * dx + dy * dy + dz * dz);
    atomicAdd(&counts[d], 1);

    float m = dist;
    #pragma unroll
    for (int o = 32; o >= 1; o >>= 1)
        m = fmaxf(m, __shfl_xor(m, o));
    if ((threadIdx.x & 63) == 0) smax[threadIdx.x >> 6] = m;
    __syncthreads();
    if (threadIdx.x == 0)
        blockmax[blockIdx.x] = fmaxf(fmaxf(smax[0], smax[1]), fmaxf(smax[2], smax[3]));
}

// ---------------- 3-kernel exclusive scan over counts -----------------------
__global__ __launch_bounds__(256) void k_scan1(const int* __restrict__ counts,
    int* __restrict__ loc, int* __restrict__ bsum)
{
    __shared__ int sd[256];
    int i = blockIdx.x * 256 + threadIdx.x;
    int v = (i < NN) ? counts[i] : 0;
    sd[threadIdx.x] = v;
    __syncthreads();
    for (int ofs = 1; ofs < 256; ofs <<= 1) {
        int t = (threadIdx.x >= ofs) ? sd[threadIdx.x - ofs] : 0;
        __syncthreads();
        sd[threadIdx.x] += t;
        __syncthreads();
    }
    int incl = sd[threadIdx.x];
    if (i < NN) loc[i] = incl - v;
    if (threadIdx.x == 255) bsum[blockIdx.x] = incl;
}

// block 0: exclusive scan of bsum; block 1: dmax reduce over blockmax
__global__ __launch_bounds__(256) void k_scan2dmax(const int* __restrict__ bsum,
    int* __restrict__ bofs, int nb,
    const float* __restrict__ blockmax, float* __restrict__ dmax, int nmb)
{
    if (blockIdx.x == 0) {
        __shared__ int sd[256];
        int v = (threadIdx.x < nb) ? bsum[threadIdx.x] : 0;
        sd[threadIdx.x] = v;
        __syncthreads();
        for (int ofs = 1; ofs < 256; ofs <<= 1) {
            int t = (threadIdx.x >= ofs) ? sd[threadIdx.x - ofs] : 0;
            __syncthreads();
            sd[threadIdx.x] += t;
            __syncthreads();
        }
        bofs[threadIdx.x] = sd[threadIdx.x] - v;
    } else {
        __shared__ float smax[4];
        float m = 0.f;
        for (int i = threadIdx.x; i < nmb; i += 256) m = fmaxf(m, blockmax[i]);
        #pragma unroll
        for (int o = 32; o >= 1; o >>= 1)
            m = fmaxf(m, __shfl_xor(m, o));
        if ((threadIdx.x & 63) == 0) smax[threadIdx.x >> 6] = m;
        __syncthreads();
        if (threadIdx.x == 0)
            dmax[0] = fmaxf(fmaxf(smax[0], smax[1]), fmaxf(smax[2], smax[3]));
    }
}

__global__ __launch_bounds__(256) void k_scan3(const int* __restrict__ loc,
    const int* __restrict__ bofs, int* __restrict__ offs)
{
    int i = blockIdx.x * 256 + threadIdx.x;
    if (i < NN) offs[i] = loc[i] + bofs[blockIdx.x];
    if (i == 0) offs[NN] = EE;
}

// ---------------- edge pass 2: recompute geometry + ab + SoA CSR record -----
// dist/dsum recomputed from ei+pos4 (bit-identical ops to pass 1) instead of
// a 12.8MB dde round-trip; pos4 (800KB) is L2-resident on the re-read.
__global__ __launch_bounds__(256) void k_fill(
    const int* __restrict__ ei, const float4* __restrict__ pos4,
    const float* __restrict__ dmaxp,
    const float* __restrict__ vfp, const float* __restrict__ vpar,
    const int* __restrict__ offs, int* __restrict__ cursor,
    int* __restrict__ srcs, uint2* __restrict__ abe)
{
    int e = blockIdx.x * 256 + threadIdx.x;       // grid covers EE exactly
    int s = ei[e], d = ei[EE + e];
    float4 ps = pos4[s], pd = pos4[d];
    float dx = ps.x - pd.x, dy = ps.y - pd.y, dz = ps.z - pd.z;
    float dist = sqrtf(dx * dx + dy * dy + dz * dz);
    float rinv = 1.f / (dist + 1e-8f);
    float dsum = (dx + dy + dz) * rinv;
    float r = dist / dmaxp[0];
    float vf = vfp[0];
    H4 p;
    #pragma unroll
    for (int k = 0; k < 4; ++k) {
        float v = vf * fminf(r, vpar[k]);
        p.h[k] = (_Float16)(sqrtf(1.f - v * v + 1e-8f) / (1.f + v * dsum));
    }
    int slot = offs[d] + atomicAdd(&cursor[d], 1);
    srcs[slot] = s;
    abe[slot] = p.u;
}

// ---------------- aggregation + fused BN partial stats ----------------------
// Full wave per edge (lane owns msg uint col = lane). Grid-stride: 2048
// blocks = 32 waves/CU resident, 8192 waves cover 50000 nodes (~6 each).
// SoA edge records via wave-uniform indices (SGPR path); width-8 batches
// with zeroed tail coefficients — no serial tail.
__global__ __launch_bounds__(256) void k_agg(
    const int* __restrict__ offs, const int* __restrict__ srcs,
    const uint2* __restrict__ abe, const unsigned int* __restrict__ msg,
    unsigned int* __restrict__ aggb,         // bf16 [NN][512] as uint[NN][256]
    float* __restrict__ bn_psum, float* __restrict__ bn_psq)
{
    __shared__ float s_bn[4 * 1024];         // [wave][16 vals][64 lanes]
    const int tid = threadIdx.x;
    const int lane = tid & 63;
    const int w = __builtin_amdgcn_readfirstlane(tid >> 6);
    const int gw = (blockIdx.x << 2) | w;    // 0..8191

    float ps0 = 0, ps1 = 0, ps2 = 0, ps3 = 0, ps4 = 0, ps5 = 0, ps6 = 0, ps7 = 0;
    float pq0 = 0, pq1 = 0, pq2 = 0, pq3 = 0, pq4 = 0, pq5 = 0, pq6 = 0, pq7 = 0;

    for (int n = gw; n < NN; n += 8192) {
        int st = __builtin_amdgcn_readfirstlane(offs[n]);
        int en = __builtin_amdgcn_readfirstlane(offs[n + 1]);
        float a00 = 0, a10 = 0, a20 = 0, a30 = 0, a01 = 0, a11 = 0, a21 = 0, a31 = 0;

        for (int e = st; e < en; e += 8) {
            int idx[8];
            unsigned int uu[8];
            #pragma unroll
            for (int j = 0; j < 8; ++j) {
                int ee = e + j;
                idx[j] = (ee < en) ? ee : en - 1;       // wave-uniform clamp
            }
            #pragma unroll
            for (int j = 0; j < 8; ++j)
                uu[j] = msg[(size_t)srcs[idx[j]] * 64 + lane];
            #pragma unroll
            for (int j = 0; j < 8; ++j) {
                uint2 a = abe[idx[j]];
                bool valid = (e + j) < en;              // wave-uniform
                a.x = valid ? a.x : 0u;
                a.y = valid ? a.y : 0u;
                H4 p; p.u = a;
                float m0 = bf_lo(uu[j]), m1 = bf_hi(uu[j]);
                a00 = fmaf((float)p.h[0], m0, a00); a01 = fmaf((float)p.h[0], m1, a01);
                a10 = fmaf((float)p.h[1], m0, a10); a11 = fmaf((float)p.h[1], m1, a11);
                a20 = fmaf((float)p.h[2], m0, a20); a21 = fmaf((float)p.h[2], m1, a21);
                a30 = fmaf((float)p.h[3], m0, a30); a31 = fmaf((float)p.h[3], m1, a31);
            }
        }

        unsigned int* o = aggb + (size_t)n * 256 + lane;   // col c = k*128 + h
        o[0]   = pack2(a00, a01);
        o[64]  = pack2(a10, a11);
        o[128] = pack2(a20, a21);
        o[192] = pack2(a30, a31);

        ps0 += a00; pq0 = fmaf(a00, a00, pq0);
        ps1 += a01; pq1 = fmaf(a01, a01, pq1);
        ps2 += a10; pq2 = fmaf(a10, a10, pq2);
        ps3 += a11; pq3 = fmaf(a11, a11, pq3);
        ps4 += a20; pq4 = fmaf(a20, a20, pq4);
        ps5 += a21; pq5 = fmaf(a21, a21, pq5);
        ps6 += a30; pq6 = fmaf(a30, a30, pq6);
        ps7 += a31; pq7 = fmaf(a31, a31, pq7);
    }

    // per-wave partials -> LDS
    float* sw = s_bn + w * 1024 + lane;
    sw[0 * 64] = ps0; sw[1 * 64] = ps1; sw[2 * 64] = ps2; sw[3 * 64] = ps3;
    sw[4 * 64] = ps4; sw[5 * 64] = ps5; sw[6 * 64] = ps6; sw[7 * 64] = ps7;
    sw[8 * 64] = pq0; sw[9 * 64] = pq1; sw[10 * 64] = pq2; sw[11 * 64] = pq3;
    sw[12 * 64] = pq4; sw[13 * 64] = pq5; sw[14 * 64] = pq6; sw[15 * 64] = pq7;
    __syncthreads();

    // cross-wave reduce + one atomic per entry (1024 entries / 256 threads)
    int part = (blockIdx.x & 31) * 512;
    #pragma unroll
    for (int k = 0; k < 4; ++k) {
        int idx = tid + k * 256;                 // 0..1023
        float s = s_bn[idx] + s_bn[1024 + idx] + s_bn[2048 + idx] + s_bn[3072 + idx];
        int v = idx >> 6, ln = idx & 63;
        int col = ((v & 7) >> 1) * 128 + 2 * ln + (v & 1);
        if (v < 8) atomicAdd(&bn_psum[part + col], s);
        else       atomicAdd(&bn_psq[part + col], s);
    }
}

__global__ __launch_bounds__(256) void k_bnfin(const float* __restrict__ bn_psum,
    const float* __restrict__ bn_psq, const float* __restrict__ bng,
    const float* __restrict__ bnbeta, float* __restrict__ bns, float* __restrict__ bnbv)
{
    int c = blockIdx.x * 256 + threadIdx.x;
    if (c >= 512) return;
    float s = 0.f, q = 0.f;
    #pragma unroll 8
    for (int p = 0; p < 32; ++p) {
        s += bn_psum[p * 512 + c];
        q += bn_psq[p * 512 + c];
    }
    float mean = s * (1.f / NN);
    float var = q * (1.f / NN) - mean * mean;
    float sc = bng[c] / sqrtf(var + 1e-5f);
    bns[c] = sc;
    bnbv[c] = bnbeta[c] - mean * sc;
}

// ---------------- final fused MFMA: col-split waves, 32-node tile -----------
// R4 geometry (known best: 4 blocks/CU). Only change vs R4: staging uses
// uint4 (16B) loads — 8 iters x 128B-in-flight/thread vs 32 iters x 4B —
// 4x the staging MLP, 4x fewer load instructions (the latency-bound phase).
__global__ __launch_bounds__(256) void k_final(
    const unsigned int* __restrict__ aggb,
    const float* __restrict__ bns, const float* __restrict__ bnb,
    const unsigned short* __restrict__ w1p, const float* __restrict__ b1,
    const float* __restrict__ lng, const float* __restrict__ lnb,
    const unsigned short* __restrict__ w2p, const float* __restrict__ b2,
    float* __restrict__ out)
{
    __shared__ unsigned int s_z[32 * 260];   // 33280 B; t matrix aliases below
    __shared__ float s_lng[256], s_lnb[256];
    __shared__ float s_ps[2][32], s_pq[2][32];
    __shared__ float s_mu[32], s_iv[32];
    unsigned short* s_ts = reinterpret_cast<unsigned short*>(s_z);  // [32][264]

    const int tid = threadIdx.x;
    const int w = tid >> 6, lane = tid & 63, l15 = lane & 15, g = lane >> 4;
    const int ng = w & 1, ch = w >> 1;
    const int n0 = blockIdx.x * 32;

    s_lng[tid] = lng[tid];
    s_lnb[tid] = lnb[tid];

    // stage z = bf16(relu(agg*scale+shift)); uint4: thread owns ucols 4t..4t+3
    // of row (i*4 + tid>>6) -> bf16 cols 8t..8t+7 (t = tid&63)
    const int t6 = tid & 63, r0 = tid >> 6;
    f32x4 sva = *reinterpret_cast<const f32x4*>(bns + 8 * t6);
    f32x4 svb = *reinterpret_cast<const f32x4*>(bns + 8 * t6 + 4);
    f32x4 bva = *reinterpret_cast<const f32x4*>(bnb + 8 * t6);
    f32x4 bvb = *reinterpret_cast<const f32x4*>(bnb + 8 * t6 + 4);
    #pragma unroll
    for (int i = 0; i < 8; ++i) {
        int row = i * 4 + r0;
        int ar = (n0 + row < NN) ? n0 + row : NN - 1;
        uint4 u = *reinterpret_cast<const uint4*>(aggb + (size_t)ar * 256 + t6 * 4);
        uint4 o;
        o.x = pack2(fmaxf(fmaf(bf_lo(u.x), sva[0], bva[0]), 0.f),
                    fmaxf(fmaf(bf_hi(u.x), sva[1], bva[1]), 0.f));
        o.y = pack2(fmaxf(fmaf(bf_lo(u.y), sva[2], bva[2]), 0.f),
                    fmaxf(fmaf(bf_hi(u.y), sva[3], bva[3]), 0.f));
        o.z = pack2(fmaxf(fmaf(bf_lo(u.z), svb[0], bvb[0]), 0.f),
                    fmaxf(fmaf(bf_hi(u.z), svb[1], bvb[1]), 0.f));
        o.w = pack2(fmaxf(fmaf(bf_lo(u.w), svb[2], bvb[2]), 0.f),
                    fmaxf(fmaf(bf_hi(u.w), svb[3], bvb[3]), 0.f));
        *reinterpret_cast<uint4*>(&s_z[row * 260 + t6 * 4]) = o;
    }
    __syncthreads();

    // ---------------- GEMM1: rows ng*16+l15, out tiles ch*8+j (j<8) ---------
    const unsigned int* zrow = s_z + (ng * 16 + l15) * 260;
    const int4* B1 = reinterpret_cast<const int4*>(w1p);
    f32x4 acc1[8];
    #pragma unroll
    for (int j = 0; j < 8; ++j) acc1[j] = (f32x4){0.f, 0.f, 0.f, 0.f};

    #pragma unroll 2
    for (int kk = 0; kk < 16; ++kk) {
        Frag16B a;
        a.i = *reinterpret_cast<const int4*>(zrow + kk * 16 + g * 4);
        #pragma unroll
        for (int j = 0; j < 8; ++j) {
            Frag16B b; b.i = B1[(kk * 16 + ch * 8 + j) * 64 + lane];
            acc1[j] = __builtin_amdgcn_mfma_f32_16x16x32_bf16(a.s, b.s, acc1[j], 0, 0, 0);
        }
    }
    __syncthreads();   // all z reads done before t overwrites the buffer

    // ---------------- bias + t stash + LN partials (per col-half) -----------
    float b1v[8];
    #pragma unroll
    for (int j = 0; j < 8; ++j) b1v[j] = b1[(ch * 8 + j) * 16 + l15];

    float ssum[4] = {0, 0, 0, 0}, sq[4] = {0, 0, 0, 0};
    #pragma unroll
    for (int j = 0; j < 8; ++j) {
        float bvv = b1v[j];
        #pragma unroll
        for (int r = 0; r < 4; ++r) {
            float tv = acc1[j][r] + bvv;
            ssum[r] += tv;
            sq[r] = fmaf(tv, tv, sq[r]);
            s_ts[(ng * 16 + g * 4 + r) * 264 + (ch * 8 + j) * 16 + l15] = f2bf(tv);
        }
    }
    #pragma unroll
    for (int m = 1; m < 16; m <<= 1) {
        #pragma unroll
        for (int r = 0; r < 4; ++r) {
            ssum[r] += __shfl_xor(ssum[r], m);
            sq[r]   += __shfl_xor(sq[r], m);
        }
    }
    if (l15 < 4) {
        float svv = l15 == 0 ? ssum[0] : l15 == 1 ? ssum[1] : l15 == 2 ? ssum[2] : ssum[3];
        float qv  = l15 == 0 ? sq[0]   : l15 == 1 ? sq[1]   : l15 == 2 ? sq[2]   : sq[3];
        s_ps[ch][ng * 16 + g * 4 + l15] = svv;
        s_pq[ch][ng * 16 + g * 4 + l15] = qv;
    }
    __syncthreads();

    if (tid < 32) {
        float s = s_ps[0][tid] + s_ps[1][tid];
        float q = s_pq[0][tid] + s_pq[1][tid];
        float mean = s * (1.f / 256.f);
        float var = q * (1.f / 256.f) - mean * mean;
        s_mu[tid] = mean;
        s_iv[tid] = 1.f / sqrtf(var + 1e-5f);
    }
    __syncthreads();

    // ---------------- GEMM2: K=256 over t; out tiles ch*4+j (j<4) -----------
    const float mu_m = s_mu[ng * 16 + l15];
    const float iv_m = s_iv[ng * 16 + l15];
    const int4* B2 = reinterpret_cast<const int4*>(w2p);
    const unsigned short* trow = s_ts + (ng * 16 + l15) * 264;

    f32x4 acc2[4];
    #pragma unroll
    for (int j = 0; j < 4; ++j) acc2[j] = (f32x4){0.f, 0.f, 0.f, 0.f};

    #pragma unroll 2
    for (int kk = 0; kk < 8; ++kk) {
        const int kb = kk * 32 + g * 8;
        int4 traw = *reinterpret_cast<const int4*>(trow + kb);
        const unsigned short* tu = reinterpret_cast<const unsigned short*>(&traw);
        short8 af;
        #pragma unroll
        for (int j = 0; j < 8; ++j) {
            float tv = __uint_as_float(((unsigned int)tu[j]) << 16);
            float rn = fmaxf(fmaf((tv - mu_m) * iv_m, s_lng[kb + j], s_lnb[kb + j]), 0.f);
            af[j] = (short)f2bf(rn);
        }
        #pragma unroll
        for (int j = 0; j < 4; ++j) {
            Frag16B b; b.i = B2[(kk * 8 + ch * 4 + j) * 64 + lane];
            acc2[j] = __builtin_amdgcn_mfma_f32_16x16x32_bf16(af, b.s, acc2[j], 0, 0, 0);
        }
    }

    float b2v[4];
    #pragma unroll
    for (int j = 0; j < 4; ++j) b2v[j] = b2[(ch * 4 + j) * 16 + l15];

    #pragma unroll
    for (int j = 0; j < 4; ++j) {
        #pragma unroll
        for (int r = 0; r < 4; ++r) {
            int n = n0 + ng * 16 + g * 4 + r;
            if (n < NN)
                out[(size_t)n * 128 + (ch * 4 + j) * 16 + l15] = acc2[j][r] + b2v[j];
        }
    }
}

// ---------------------------------------------------------------------------
extern "C" void kernel_launch(void* const* d_in, const int* in_sizes, int n_in,
                              void* d_out, int out_size, void* d_ws, size_t ws_size,
                              hipStream_t stream)
{
    const float* x    = (const float*)d_in[0];
    const int*   ei   = (const int*)d_in[1];
    const float* pos  = (const float*)d_in[2];
    const float* wft  = (const float*)d_in[3];
    const float* bft  = (const float*)d_in[4];
    const float* wcv  = (const float*)d_in[5];
    const float* bcv  = (const float*)d_in[6];
    const float* vfp  = (const float*)d_in[7];
    const float* vpar = (const float*)d_in[8];
    const float* bng  = (const float*)d_in[9];
    const float* bnbe = (const float*)d_in[10];
    const float* att  = (const float*)d_in[11];
    const float* w1   = (const float*)d_in[12];
    const float* b1   = (const float*)d_in[13];
    const float* lng  = (const float*)d_in[14];
    const float* lnb  = (const float*)d_in[15];
    const float* w2   = (const float*)d_in[16];
    const float* b2   = (const float*)d_in[17];
    float* out = (float*)d_out;

    float* ws = (float*)d_ws;
    size_t off = 0;
    unsigned int* msg  = (unsigned int*)(ws + off); off += (size_t)NN * 64;    // bf16 [N][128]
    unsigned int* aggb = (unsigned int*)(ws + off); off += (size_t)NN * 256;   // bf16 [N][512]
    unsigned short* w1p  = (unsigned short*)(ws + off); off += 65536;
    unsigned short* w2p  = (unsigned short*)(ws + off); off += 16384;
    unsigned short* wftp = (unsigned short*)(ws + off); off += 8192;
    unsigned short* wcvp = (unsigned short*)(ws + off); off += 8192;
    float4* pos4 = (float4*)(ws + off); off += (size_t)NN * 4;
    float* bns  = ws + off; off += 512;
    float* bnbv = ws + off; off += 512;
    int* srcs   = (int*)(ws + off); off += (size_t)EE;          // SoA CSR: src
    uint2* abe  = (uint2*)(ws + off); off += (size_t)EE * 2;    // SoA CSR: ab01/ab23
    int* offs   = (int*)(ws + off); off += NN + 4;
    int* loc    = (int*)(ws + off); off += NN;
    int* bsum   = (int*)(ws + off); off += 256;
    int* bofs   = (int*)(ws + off); off += 256;
    float* blockmax = ws + off; off += 3136;
    float* dmax = ws + off; off += 4;
    size_t zstart = off;
    float* bn_psum = ws + off; off += 32 * 512;
    float* bn_psq  = ws + off; off += 32 * 512;
    int* counts = (int*)(ws + off); off += NN;
    int* cursor = (int*)(ws + off); off += NN;
    size_t zend = off;

    hipMemsetAsync(ws + zstart, 0, (zend - zstart) * sizeof(float), stream);

    k_prep<<<196, 256, 0, stream>>>(w1, att, w2, wft, wcv, pos, w1p, w2p, wftp, wcvp, pos4);
    k_ft_conv<<<782, 256, 0, stream>>>(x, wftp, bft, wcvp, bcv, msg);
    k_edge_pass1<<<3125, 256, 0, stream>>>(ei, pos4, blockmax, counts);
    k_scan1<<<196, 256, 0, stream>>>(counts, loc, bsum);
    k_scan2dmax<<<2, 256, 0, stream>>>(bsum, bofs, 196, blockmax, dmax, 3125);
    k_scan3<<<196, 256, 0, stream>>>(loc, bofs, offs);
    k_fill<<<3125, 256, 0, stream>>>(ei, pos4, dmax, vfp, vpar, offs, cursor, srcs, abe);
    k_agg<<<2048, 256, 0, stream>>>(offs, srcs, abe, msg, aggb, bn_psum, bn_psq);
    k_bnfin<<<2, 256, 0, stream>>>(bn_psum, bn_psq, bng, bnbe, bns, bnbv);
    k_final<<<1563, 256, 0, stream>>>(aggb, bns, bnbv, w1p, b1, lng, lnb, w2p, b2, out);
}

// Round 8
// 310.601 us; speedup vs baseline: 1.1532x; 1.0276x over previous
//
#include <hip/hip_runtime.h>
#include <hip/hip_bf16.h>

#define NN 50000
#define EE 800000

typedef short short8 __attribute__((ext_vector_type(8)));
typedef float f32x4 __attribute__((ext_vector_type(4)));

union Frag16B { short8 s; int4 i; };
union H4 { _Float16 h[4]; uint2 u; };

static __device__ __forceinline__ unsigned short f2bf(float f) {
    union { float f; unsigned u; } v; v.f = f;
    unsigned r = v.u + 0x7FFF + ((v.u >> 16) & 1);   // RNE
    return (unsigned short)(r >> 16);
}
static __device__ __forceinline__ float bf_lo(unsigned int u) {
    return __uint_as_float(u << 16);
}
static __device__ __forceinline__ float bf_hi(unsigned int u) {
    return __uint_as_float(u & 0xFFFF0000u);
}
static __device__ __forceinline__ unsigned int pack2(float a, float b) {
    return (unsigned int)f2bf(a) | ((unsigned int)f2bf(b) << 16);
}

// ---------------- prep: fragment-major bf16 weight packing + pos->float4 ----
__global__ __launch_bounds__(256) void k_prep(
    const float* __restrict__ w1,  const float* __restrict__ att,
    const float* __restrict__ w2,
    const float* __restrict__ wft, const float* __restrict__ wcv,
    const float* __restrict__ pos,
    unsigned short* __restrict__ w1p, unsigned short* __restrict__ w2p,
    unsigned short* __restrict__ wftp, unsigned short* __restrict__ wcvp,
    float4* __restrict__ pos4)
{
    int gth = blockIdx.x * 256 + threadIdx.x;
    int lane = gth & 63, l15 = lane & 15, gg = lane >> 4;
    if (gth < 16384) {                       // w1p: kk<16, t<16, fold att[col]
        int t = (gth >> 6) & 15, kk = gth >> 10;
        int row = t * 16 + l15, c0 = kk * 32 + gg * 8;
        unsigned int pk[4];
        #pragma unroll
        for (int j = 0; j < 4; ++j) {
            int c = c0 + 2 * j;
            pk[j] = pack2(w1[row * 512 + c] * att[c],
                          w1[row * 512 + c + 1] * att[c + 1]);
        }
        *reinterpret_cast<uint4*>(w1p + (size_t)gth * 8) = make_uint4(pk[0], pk[1], pk[2], pk[3]);
    }
    if (gth < 4096) {                        // w2p: kk<8, t<8
        int t = (gth >> 6) & 7, kk = gth >> 9;
        int row = t * 16 + l15, c0 = kk * 32 + gg * 8;
        unsigned int pk[4];
        #pragma unroll
        for (int j = 0; j < 4; ++j) {
            int c = c0 + 2 * j;
            pk[j] = pack2(w2[row * 256 + c], w2[row * 256 + c + 1]);
        }
        *reinterpret_cast<uint4*>(w2p + (size_t)gth * 8) = make_uint4(pk[0], pk[1], pk[2], pk[3]);
    }
    if (gth < 2048) {                        // wftp / wcvp: kk<4, t<8
        int t = (gth >> 6) & 7, kk = gth >> 9;
        int row = t * 16 + l15, c0 = kk * 32 + gg * 8;
        unsigned int pa[4], pb[4];
        #pragma unroll
        for (int j = 0; j < 4; ++j) {
            int c = c0 + 2 * j;
            pa[j] = pack2(wft[row * 128 + c], wft[row * 128 + c + 1]);
            pb[j] = pack2(wcv[row * 128 + c], wcv[row * 128 + c + 1]);
        }
        *reinterpret_cast<uint4*>(wftp + (size_t)gth * 8) = make_uint4(pa[0], pa[1], pa[2], pa[3]);
        *reinterpret_cast<uint4*>(wcvp + (size_t)gth * 8) = make_uint4(pb[0], pb[1], pb[2], pb[3]);
    }
    if (gth < NN) {                          // pos -> padded float4
        pos4[gth] = make_float4(pos[gth * 3 + 0], pos[gth * 3 + 1], pos[gth * 3 + 2], 0.f);
    }
}

// ---------------- fused node GEMMs (MFMA): msg = (relu(x WftT+bft)) WcvT + bcv
__global__ __launch_bounds__(256) void k_ft_conv(
    const float* __restrict__ x,
    const unsigned short* __restrict__ wftp, const float* __restrict__ bft,
    const unsigned short* __restrict__ wcvp, const float* __restrict__ bcv,
    unsigned int* __restrict__ msg)          // bf16 [NN][128] as uint[NN][64]
{
    __shared__ unsigned int s_x[64 * 68];    // bf16 tile (reused for out)
    __shared__ unsigned short s_h[64 * 136];
    const int tid = threadIdx.x;
    const int w = tid >> 6, lane = tid & 63, l15 = lane & 15, g = lane >> 4;
    const int n0 = blockIdx.x * 64;

    #pragma unroll
    for (int i = 0; i < 8; ++i) {
        int lin = tid + i * 256;
        int row = lin >> 5, c4 = lin & 31;
        int ar = (n0 + row < NN) ? n0 + row : NN - 1;
        float4 v = *reinterpret_cast<const float4*>(x + (size_t)ar * 128 + c4 * 4);
        s_x[row * 68 + c4 * 2]     = pack2(v.x, v.y);
        s_x[row * 68 + c4 * 2 + 1] = pack2(v.z, v.w);
    }
    __syncthreads();

    float bftv[8], bcvv[8];
    #pragma unroll
    for (int t = 0; t < 8; ++t) { bftv[t] = bft[t * 16 + l15]; bcvv[t] = bcv[t * 16 + l15]; }

    const int4* Bf = reinterpret_cast<const int4*>(wftp);
    f32x4 acc[8];
    #pragma unroll
    for (int t = 0; t < 8; ++t) acc[t] = (f32x4){0.f, 0.f, 0.f, 0.f};
    #pragma unroll
    for (int kk = 0; kk < 4; ++kk) {
        Frag16B a;
        a.i = *reinterpret_cast<const int4*>(&s_x[(w * 16 + l15) * 68 + kk * 16 + g * 4]);
        #pragma unroll
        for (int t = 0; t < 8; ++t) {
            Frag16B b; b.i = Bf[(kk * 8 + t) * 64 + lane];
            acc[t] = __builtin_amdgcn_mfma_f32_16x16x32_bf16(a.s, b.s, acc[t], 0, 0, 0);
        }
    }
    #pragma unroll
    for (int t = 0; t < 8; ++t)
        #pragma unroll
        for (int r = 0; r < 4; ++r)
            s_h[(w * 16 + g * 4 + r) * 136 + t * 16 + l15] =
                f2bf(fmaxf(acc[t][r] + bftv[t], 0.f));
    __syncthreads();

    const int4* Bc = reinterpret_cast<const int4*>(wcvp);
    #pragma unroll
    for (int t = 0; t < 8; ++t) acc[t] = (f32x4){0.f, 0.f, 0.f, 0.f};
    #pragma unroll
    for (int kk = 0; kk < 4; ++kk) {
        Frag16B a;
        a.i = *reinterpret_cast<const int4*>(&s_h[(w * 16 + l15) * 136 + kk * 32 + g * 8]);
        #pragma unroll
        for (int t = 0; t < 8; ++t) {
            Frag16B b; b.i = Bc[(kk * 8 + t) * 64 + lane];
            acc[t] = __builtin_amdgcn_mfma_f32_16x16x32_bf16(a.s, b.s, acc[t], 0, 0, 0);
        }
    }
    unsigned short* s_o = reinterpret_cast<unsigned short*>(s_x);
    #pragma unroll
    for (int t = 0; t < 8; ++t)
        #pragma unroll
        for (int r = 0; r < 4; ++r)
            s_o[(w * 16 + g * 4 + r) * 136 + t * 16 + l15] = f2bf(acc[t][r] + bcvv[t]);
    __syncthreads();
    #pragma unroll
    for (int i = 0; i < 8; ++i) {
        int lin = tid + i * 256;
        int row = lin >> 5, cu2 = lin & 31;
        if (n0 + row < NN) {
            uint2 v;
            v.x = s_x[row * 68 + cu2 * 2];
            v.y = s_x[row * 68 + cu2 * 2 + 1];
            *reinterpret_cast<uint2*>(msg + (size_t)(n0 + row) * 64 + cu2 * 2) = v;
        }
    }
}

// ---------------- edge pass 1: degree + block max only (no dde record) ------
__global__ __launch_bounds__(256) void k_edge_pass1(
    const int* __restrict__ ei, const float4* __restrict__ pos4,
    float* __restrict__ blockmax, int* __restrict__ counts)
{
    __shared__ float smax[4];
    int e = blockIdx.x * 256 + threadIdx.x;       // grid covers EE exactly
    int s = ei[e], d = ei[EE + e];
    float4 ps = pos4[s], pd = pos4[d];
    float dx = ps.x - pd.x, dy = ps.y - pd.y, dz = ps.z - pd.z;
    float dist = sqrtf(dx * dx + dy * dy + dz * dz);
    atomicAdd(&counts[d], 1);

    float m = dist;
    #pragma unroll
    for (int o = 32; o >= 1; o >>= 1)
        m = fmaxf(m, __shfl_xor(m, o));
    if ((threadIdx.x & 63) == 0) smax[threadIdx.x >> 6] = m;
    __syncthreads();
    if (threadIdx.x == 0)
        blockmax[blockIdx.x] = fmaxf(fmaxf(smax[0], smax[1]), fmaxf(smax[2], smax[3]));
}

// ---------------- 3-kernel exclusive scan over counts -----------------------
__global__ __launch_bounds__(256) void k_scan1(const int* __restrict__ counts,
    int* __restrict__ loc, int* __restrict__ bsum)
{
    __shared__ int sd[256];
    int i = blockIdx.x * 256 + threadIdx.x;
    int v = (i < NN) ? counts[i] : 0;
    sd[threadIdx.x] = v;
    __syncthreads();
    for (int ofs = 1; ofs < 256; ofs <<= 1) {
        int t = (threadIdx.x >= ofs) ? sd[threadIdx.x - ofs] : 0;
        __syncthreads();
        sd[threadIdx.x] += t;
        __syncthreads();
    }
    int incl = sd[threadIdx.x];
    if (i < NN) loc[i] = incl - v;
    if (threadIdx.x == 255) bsum[blockIdx.x] = incl;
}

// block 0: exclusive scan of bsum; block 1: dmax reduce over blockmax
__global__ __launch_bounds__(256) void k_scan2dmax(const int* __restrict__ bsum,
    int* __restrict__ bofs, int nb,
    const float* __restrict__ blockmax, float* __restrict__ dmax, int nmb)
{
    if (blockIdx.x == 0) {
        __shared__ int sd[256];
        int v = (threadIdx.x < nb) ? bsum[threadIdx.x] : 0;
        sd[threadIdx.x] = v;
        __syncthreads();
        for (int ofs = 1; ofs < 256; ofs <<= 1) {
            int t = (threadIdx.x >= ofs) ? sd[threadIdx.x - ofs] : 0;
            __syncthreads();
            sd[threadIdx.x] += t;
            __syncthreads();
        }
        bofs[threadIdx.x] = sd[threadIdx.x] - v;
    } else {
        __shared__ float smax[4];
        float m = 0.f;
        for (int i = threadIdx.x; i < nmb; i += 256) m = fmaxf(m, blockmax[i]);
        #pragma unroll
        for (int o = 32; o >= 1; o >>= 1)
            m = fmaxf(m, __shfl_xor(m, o));
        if ((threadIdx.x & 63) == 0) smax[threadIdx.x >> 6] = m;
        __syncthreads();
        if (threadIdx.x == 0)
            dmax[0] = fmaxf(fmaxf(smax[0], smax[1]), fmaxf(smax[2], smax[3]));
    }
}

__global__ __launch_bounds__(256) void k_scan3(const int* __restrict__ loc,
    const int* __restrict__ bofs, int* __restrict__ offs)
{
    int i = blockIdx.x * 256 + threadIdx.x;
    if (i < NN) offs[i] = loc[i] + bofs[blockIdx.x];
    if (i == 0) offs[NN] = EE;
}

// ---------------- edge pass 2: recompute geometry + ab + SoA CSR record -----
__global__ __launch_bounds__(256) void k_fill(
    const int* __restrict__ ei, const float4* __restrict__ pos4,
    const float* __restrict__ dmaxp,
    const float* __restrict__ vfp, const float* __restrict__ vpar,
    const int* __restrict__ offs, int* __restrict__ cursor,
    int* __restrict__ srcs, uint2* __restrict__ abe)
{
    int e = blockIdx.x * 256 + threadIdx.x;       // grid covers EE exactly
    int s = ei[e], d = ei[EE + e];
    float4 ps = pos4[s], pd = pos4[d];
    float dx = ps.x - pd.x, dy = ps.y - pd.y, dz = ps.z - pd.z;
    float dist = sqrtf(dx * dx + dy * dy + dz * dz);
    float rinv = 1.f / (dist + 1e-8f);
    float dsum = (dx + dy + dz) * rinv;
    float r = dist / dmaxp[0];
    float vf = vfp[0];
    H4 p;
    #pragma unroll
    for (int k = 0; k < 4; ++k) {
        float v = vf * fminf(r, vpar[k]);
        p.h[k] = (_Float16)(sqrtf(1.f - v * v + 1e-8f) / (1.f + v * dsum));
    }
    int slot = offs[d] + atomicAdd(&cursor[d], 1);
    srcs[slot] = s;
    abe[slot] = p.u;
}

// ---------------- aggregation + fused BN partial stats ----------------------
__global__ __launch_bounds__(256) void k_agg(
    const int* __restrict__ offs, const int* __restrict__ srcs,
    const uint2* __restrict__ abe, const unsigned int* __restrict__ msg,
    unsigned int* __restrict__ aggb,         // bf16 [NN][512] as uint[NN][256]
    float* __restrict__ bn_psum, float* __restrict__ bn_psq)
{
    __shared__ float s_bn[4 * 1024];         // [wave][16 vals][64 lanes]
    const int tid = threadIdx.x;
    const int lane = tid & 63;
    const int w = __builtin_amdgcn_readfirstlane(tid >> 6);
    const int gw = (blockIdx.x << 2) | w;    // 0..8191

    float ps0 = 0, ps1 = 0, ps2 = 0, ps3 = 0, ps4 = 0, ps5 = 0, ps6 = 0, ps7 = 0;
    float pq0 = 0, pq1 = 0, pq2 = 0, pq3 = 0, pq4 = 0, pq5 = 0, pq6 = 0, pq7 = 0;

    for (int n = gw; n < NN; n += 8192) {
        int st = __builtin_amdgcn_readfirstlane(offs[n]);
        int en = __builtin_amdgcn_readfirstlane(offs[n + 1]);
        float a00 = 0, a10 = 0, a20 = 0, a30 = 0, a01 = 0, a11 = 0, a21 = 0, a31 = 0;

        for (int e = st; e < en; e += 8) {
            int idx[8];
            unsigned int uu[8];
            #pragma unroll
            for (int j = 0; j < 8; ++j) {
                int ee = e + j;
                idx[j] = (ee < en) ? ee : en - 1;       // wave-uniform clamp
            }
            #pragma unroll
            for (int j = 0; j < 8; ++j)
                uu[j] = msg[(size_t)srcs[idx[j]] * 64 + lane];
            #pragma unroll
            for (int j = 0; j < 8; ++j) {
                uint2 a = abe[idx[j]];
                bool valid = (e + j) < en;              // wave-uniform
                a.x = valid ? a.x : 0u;
                a.y = valid ? a.y : 0u;
                H4 p; p.u = a;
                float m0 = bf_lo(uu[j]), m1 = bf_hi(uu[j]);
                a00 = fmaf((float)p.h[0], m0, a00); a01 = fmaf((float)p.h[0], m1, a01);
                a10 = fmaf((float)p.h[1], m0, a10); a11 = fmaf((float)p.h[1], m1, a11);
                a20 = fmaf((float)p.h[2], m0, a20); a21 = fmaf((float)p.h[2], m1, a21);
                a30 = fmaf((float)p.h[3], m0, a30); a31 = fmaf((float)p.h[3], m1, a31);
            }
        }

        unsigned int* o = aggb + (size_t)n * 256 + lane;   // col c = k*128 + h
        o[0]   = pack2(a00, a01);
        o[64]  = pack2(a10, a11);
        o[128] = pack2(a20, a21);
        o[192] = pack2(a30, a31);

        ps0 += a00; pq0 = fmaf(a00, a00, pq0);
        ps1 += a01; pq1 = fmaf(a01, a01, pq1);
        ps2 += a10; pq2 = fmaf(a10, a10, pq2);
        ps3 += a11; pq3 = fmaf(a11, a11, pq3);
        ps4 += a20; pq4 = fmaf(a20, a20, pq4);
        ps5 += a21; pq5 = fmaf(a21, a21, pq5);
        ps6 += a30; pq6 = fmaf(a30, a30, pq6);
        ps7 += a31; pq7 = fmaf(a31, a31, pq7);
    }

    // per-wave partials -> LDS
    float* sw = s_bn + w * 1024 + lane;
    sw[0 * 64] = ps0; sw[1 * 64] = ps1; sw[2 * 64] = ps2; sw[3 * 64] = ps3;
    sw[4 * 64] = ps4; sw[5 * 64] = ps5; sw[6 * 64] = ps6; sw[7 * 64] = ps7;
    sw[8 * 64] = pq0; sw[9 * 64] = pq1; sw[10 * 64] = pq2; sw[11 * 64] = pq3;
    sw[12 * 64] = pq4; sw[13 * 64] = pq5; sw[14 * 64] = pq6; sw[15 * 64] = pq7;
    __syncthreads();

    // cross-wave reduce + one atomic per entry (1024 entries / 256 threads)
    int part = (blockIdx.x & 31) * 512;
    #pragma unroll
    for (int k = 0; k < 4; ++k) {
        int idx = tid + k * 256;                 // 0..1023
        float s = s_bn[idx] + s_bn[1024 + idx] + s_bn[2048 + idx] + s_bn[3072 + idx];
        int v = idx >> 6, ln = idx & 63;
        int col = ((v & 7) >> 1) * 128 + 2 * ln + (v & 1);
        if (v < 8) atomicAdd(&bn_psum[part + col], s);
        else       atomicAdd(&bn_psq[part + col], s);
    }
}

__global__ __launch_bounds__(256) void k_bnfin(const float* __restrict__ bn_psum,
    const float* __restrict__ bn_psq, const float* __restrict__ bng,
    const float* __restrict__ bnbeta, float* __restrict__ bns, float* __restrict__ bnbv)
{
    int c = blockIdx.x * 256 + threadIdx.x;
    if (c >= 512) return;
    float s = 0.f, q = 0.f;
    #pragma unroll 8
    for (int p = 0; p < 32; ++p) {
        s += bn_psum[p * 512 + c];
        q += bn_psq[p * 512 + c];
    }
    float mean = s * (1.f / NN);
    float var = q * (1.f / NN) - mean * mean;
    float sc = bng[c] / sqrtf(var + 1e-5f);
    bns[c] = sc;
    bnbv[c] = bnbeta[c] - mean * sc;
}

// ---------------- final fused MFMA: col-quarter waves, 32-node tile ---------
// R7 base (uint4 staging, 36.3KB LDS, 4 blocks/CU) with the wave remap:
// wave w owns ALL 32 rows (2 row-tiles) x its col-quarter. GEMM1: 4 j-tiles
// (cols [w*64,+64)), per kk 4 B-frags + 2 A-frags -> 8 MFMAs; B loads/wave
// 128->64, block-unique B1 traffic 256KB->128KB (no ng-pair duplicate loads).
// GEMM2: 2 j-tiles (cols [w*32,+32)) x 2 row-tiles, B2 loads 32->16.
// acc1 stays 8xf32x4 (32 VGPR) — reuse with zero occupancy cost (R5 lesson).
__global__ __launch_bounds__(256) void k_final(
    const unsigned int* __restrict__ aggb,
    const float* __restrict__ bns, const float* __restrict__ bnb,
    const unsigned short* __restrict__ w1p, const float* __restrict__ b1,
    const float* __restrict__ lng, const float* __restrict__ lnb,
    const unsigned short* __restrict__ w2p, const float* __restrict__ b2,
    float* __restrict__ out)
{
    __shared__ unsigned int s_z[32 * 260];   // 33280 B; t matrix aliases below
    __shared__ float s_lng[256], s_lnb[256];
    __shared__ float s_ps[4][32], s_pq[4][32];
    __shared__ float s_mu[32], s_iv[32];
    unsigned short* s_ts = reinterpret_cast<unsigned short*>(s_z);  // [32][264]

    const int tid = threadIdx.x;
    const int w = tid >> 6, lane = tid & 63, l15 = lane & 15, g = lane >> 4;
    const int n0 = blockIdx.x * 32;

    s_lng[tid] = lng[tid];
    s_lnb[tid] = lnb[tid];

    // stage z = bf16(relu(agg*scale+shift)); uint4: thread owns ucols 4t..4t+3
    // of row (i*4 + tid>>6) -> bf16 cols 8t..8t+7 (t = tid&63)
    const int t6 = tid & 63, r0 = tid >> 6;
    f32x4 sva = *reinterpret_cast<const f32x4*>(bns + 8 * t6);
    f32x4 svb = *reinterpret_cast<const f32x4*>(bns + 8 * t6 + 4);
    f32x4 bva = *reinterpret_cast<const f32x4*>(bnb + 8 * t6);
    f32x4 bvb = *reinterpret_cast<const f32x4*>(bnb + 8 * t6 + 4);
    #pragma unroll
    for (int i = 0; i < 8; ++i) {
        int row = i * 4 + r0;
        int ar = (n0 + row < NN) ? n0 + row : NN - 1;
        uint4 u = *reinterpret_cast<const uint4*>(aggb + (size_t)ar * 256 + t6 * 4);
        uint4 o;
        o.x = pack2(fmaxf(fmaf(bf_lo(u.x), sva[0], bva[0]), 0.f),
                    fmaxf(fmaf(bf_hi(u.x), sva[1], bva[1]), 0.f));
        o.y = pack2(fmaxf(fmaf(bf_lo(u.y), sva[2], bva[2]), 0.f),
                    fmaxf(fmaf(bf_hi(u.y), sva[3], bva[3]), 0.f));
        o.z = pack2(fmaxf(fmaf(bf_lo(u.z), svb[0], bvb[0]), 0.f),
                    fmaxf(fmaf(bf_hi(u.z), svb[1], bvb[1]), 0.f));
        o.w = pack2(fmaxf(fmaf(bf_lo(u.w), svb[2], bvb[2]), 0.f),
                    fmaxf(fmaf(bf_hi(u.w), svb[3], bvb[3]), 0.f));
        *reinterpret_cast<uint4*>(&s_z[row * 260 + t6 * 4]) = o;
    }
    __syncthreads();

    // ---------------- GEMM1: 2 row-tiles x 4 j-tiles, B block-unique --------
    const int4* B1 = reinterpret_cast<const int4*>(w1p);
    f32x4 acc1[8];                           // [rt*4 + j]
    #pragma unroll
    for (int i = 0; i < 8; ++i) acc1[i] = (f32x4){0.f, 0.f, 0.f, 0.f};

    #pragma unroll 2
    for (int kk = 0; kk < 16; ++kk) {
        Frag16B b[4];
        #pragma unroll
        for (int j = 0; j < 4; ++j)
            b[j].i = B1[(kk * 16 + w * 4 + j) * 64 + lane];
        Frag16B a[2];
        #pragma unroll
        for (int rt = 0; rt < 2; ++rt)
            a[rt].i = *reinterpret_cast<const int4*>(
                &s_z[(rt * 16 + l15) * 260 + kk * 16 + g * 4]);
        #pragma unroll
        for (int rt = 0; rt < 2; ++rt)
            #pragma unroll
            for (int j = 0; j < 4; ++j)
                acc1[rt * 4 + j] = __builtin_amdgcn_mfma_f32_16x16x32_bf16(
                    a[rt].s, b[j].s, acc1[rt * 4 + j], 0, 0, 0);
    }
    __syncthreads();   // all z reads done before t overwrites the buffer

    // ---------------- bias + t stash + LN partials (per col-quarter) --------
    float b1v[4];
    #pragma unroll
    for (int j = 0; j < 4; ++j) b1v[j] = b1[(w * 4 + j) * 16 + l15];

    float ssum[8], ssq[8];                   // [rt*4 + r]
    #pragma unroll
    for (int i = 0; i < 8; ++i) { ssum[i] = 0.f; ssq[i] = 0.f; }
    #pragma unroll
    for (int rt = 0; rt < 2; ++rt)
        #pragma unroll
        for (int j = 0; j < 4; ++j) {
            float bvv = b1v[j];
            #pragma unroll
            for (int r = 0; r < 4; ++r) {
                float tv = acc1[rt * 4 + j][r] + bvv;
                ssum[rt * 4 + r] += tv;
                ssq[rt * 4 + r] = fmaf(tv, tv, ssq[rt * 4 + r]);
                s_ts[(rt * 16 + g * 4 + r) * 264 + (w * 4 + j) * 16 + l15] = f2bf(tv);
            }
        }
    #pragma unroll
    for (int m = 1; m < 16; m <<= 1) {
        #pragma unroll
        for (int i = 0; i < 8; ++i) {
            ssum[i] += __shfl_xor(ssum[i], m);
            ssq[i]  += __shfl_xor(ssq[i], m);
        }
    }
    if (l15 == 0) {
        #pragma unroll
        for (int rt = 0; rt < 2; ++rt)
            #pragma unroll
            for (int r = 0; r < 4; ++r) {
                s_ps[w][rt * 16 + g * 4 + r] = ssum[rt * 4 + r];
                s_pq[w][rt * 16 + g * 4 + r] = ssq[rt * 4 + r];
            }
    }
    __syncthreads();

    if (tid < 32) {
        float s = s_ps[0][tid] + s_ps[1][tid] + s_ps[2][tid] + s_ps[3][tid];
        float q = s_pq[0][tid] + s_pq[1][tid] + s_pq[2][tid] + s_pq[3][tid];
        float mean = s * (1.f / 256.f);
        float var = q * (1.f / 256.f) - mean * mean;
        s_mu[tid] = mean;
        s_iv[tid] = 1.f / sqrtf(var + 1e-5f);
    }
    __syncthreads();

    // ---------------- GEMM2: K=256 over t; 2 row-tiles x 2 j-tiles ----------
    float mu_m[2], iv_m[2];
    #pragma unroll
    for (int rt = 0; rt < 2; ++rt) {
        mu_m[rt] = s_mu[rt * 16 + l15];
        iv_m[rt] = s_iv[rt * 16 + l15];
    }
    const int4* B2 = reinterpret_cast<const int4*>(w2p);

    f32x4 acc2[4];                           // [rt*2 + j]
    #pragma unroll
    for (int i = 0; i < 4; ++i) acc2[i] = (f32x4){0.f, 0.f, 0.f, 0.f};

    #pragma unroll 2
    for (int kk = 0; kk < 8; ++kk) {
        const int kb = kk * 32 + g * 8;
        Frag16B b[2];
        #pragma unroll
        for (int j = 0; j < 2; ++j)
            b[j].i = B2[(kk * 8 + w * 2 + j) * 64 + lane];
        float lg[8], lb[8];
        #pragma unroll
        for (int jj = 0; jj < 8; ++jj) { lg[jj] = s_lng[kb + jj]; lb[jj] = s_lnb[kb + jj]; }
        #pragma unroll
        for (int rt = 0; rt < 2; ++rt) {
            int4 traw = *reinterpret_cast<const int4*>(
                &s_ts[(rt * 16 + l15) * 264 + kb]);
            const unsigned short* tu = reinterpret_cast<const unsigned short*>(&traw);
            short8 af;
            #pragma unroll
            for (int jj = 0; jj < 8; ++jj) {
                float tv = __uint_as_float(((unsigned int)tu[jj]) << 16);
                float rn = fmaxf(fmaf((tv - mu_m[rt]) * iv_m[rt], lg[jj], lb[jj]), 0.f);
                af[jj] = (short)f2bf(rn);
            }
            #pragma unroll
            for (int j = 0; j < 2; ++j)
                acc2[rt * 2 + j] = __builtin_amdgcn_mfma_f32_16x16x32_bf16(
                    af, b[j].s, acc2[rt * 2 + j], 0, 0, 0);
        }
    }

    float b2v[2];
    #pragma unroll
    for (int j = 0; j < 2; ++j) b2v[j] = b2[(w * 2 + j) * 16 + l15];

    #pragma unroll
    for (int rt = 0; rt < 2; ++rt)
        #pragma unroll
        for (int j = 0; j < 2; ++j)
            #pragma unroll
            for (int r = 0; r < 4; ++r) {
                int n = n0 + rt * 16 + g * 4 + r;
                if (n < NN)
                    out[(size_t)n * 128 + (w * 2 + j) * 16 + l15] = acc2[rt * 2 + j][r] + b2v[j];
            }
}

// ---------------------------------------------------------------------------
extern "C" void kernel_launch(void* const* d_in, const int* in_sizes, int n_in,
                              void* d_out, int out_size, void* d_ws, size_t ws_size,
                              hipStream_t stream)
{
    const float* x    = (const float*)d_in[0];
    const int*   ei   = (const int*)d_in[1];
    const float* pos  = (const float*)d_in[2];
    const float* wft  = (const float*)d_in[3];
    const float* bft  = (const float*)d_in[4];
    const float* wcv  = (const float*)d_in[5];
    const float* bcv  = (const float*)d_in[6];
    const float* vfp  = (const float*)d_in[7];
    const float* vpar = (const float*)d_in[8];
    const float* bng  = (const float*)d_in[9];
    const float* bnbe = (const float*)d_in[10];
    const float* att  = (const float*)d_in[11];
    const float* w1   = (const float*)d_in[12];
    const float* b1   = (const float*)d_in[13];
    const float* lng  = (const float*)d_in[14];
    const float* lnb  = (const float*)d_in[15];
    const float* w2   = (const float*)d_in[16];
    const float* b2   = (const float*)d_in[17];
    float* out = (float*)d_out;

    float* ws = (float*)d_ws;
    size_t off = 0;
    unsigned int* msg  = (unsigned int*)(ws + off); off += (size_t)NN * 64;    // bf16 [N][128]
    unsigned int* aggb = (unsigned int*)(ws + off); off += (size_t)NN * 256;   // bf16 [N][512]
    unsigned short* w1p  = (unsigned short*)(ws + off); off += 65536;
    unsigned short* w2p  = (unsigned short*)(ws + off); off += 16384;
    unsigned short* wftp = (unsigned short*)(ws + off); off += 8192;
    unsigned short* wcvp = (unsigned short*)(ws + off); off += 8192;
    float4* pos4 = (float4*)(ws + off); off += (size_t)NN * 4;
    float* bns  = ws + off; off += 512;
    float* bnbv = ws + off; off += 512;
    int* srcs   = (int*)(ws + off); off += (size_t)EE;          // SoA CSR: src
    uint2* abe  = (uint2*)(ws + off); off += (size_t)EE * 2;    // SoA CSR: ab01/ab23
    int* offs   = (int*)(ws + off); off += NN + 4;
    int* loc    = (int*)(ws + off); off += NN;
    int* bsum   = (int*)(ws + off); off += 256;
    int* bofs   = (int*)(ws + off); off += 256;
    float* blockmax = ws + off; off += 3136;
    float* dmax = ws + off; off += 4;
    size_t zstart = off;
    float* bn_psum = ws + off; off += 32 * 512;
    float* bn_psq  = ws + off; off += 32 * 512;
    int* counts = (int*)(ws + off); off += NN;
    int* cursor = (int*)(ws + off); off += NN;
    size_t zend = off;

    hipMemsetAsync(ws + zstart, 0, (zend - zstart) * sizeof(float), stream);

    k_prep<<<196, 256, 0, stream>>>(w1, att, w2, wft, wcv, pos, w1p, w2p, wftp, wcvp, pos4);
    k_ft_conv<<<782, 256, 0, stream>>>(x, wftp, bft, wcvp, bcv, msg);
    k_edge_pass1<<<3125, 256, 0, stream>>>(ei, pos4, blockmax, counts);
    k_scan1<<<196, 256, 0, stream>>>(counts, loc, bsum);
    k_scan2dmax<<<2, 256, 0, stream>>>(bsum, bofs, 196, blockmax, dmax, 3125);
    k_scan3<<<196, 256, 0, stream>>>(loc, bofs, offs);
    k_fill<<<3125, 256, 0, stream>>>(ei, pos4, dmax, vfp, vpar, offs, cursor, srcs, abe);
    k_agg<<<2048, 256, 0, stream>>>(offs, srcs, abe, msg, aggb, bn_psum, bn_psq);
    k_bnfin<<<2, 256, 0, stream>>>(bn_psum, bn_psq, bng, bnbe, bns, bnbv);
    k_final<<<1563, 256, 0, stream>>>(aggb, bns, bnbv, w1p, b1, lng, lnb, w2p, b2, out);
}